// Round 1
// baseline (6030.050 us; speedup 1.0000x reference)
//
#include <hip/hip_runtime.h>
#include <hip/hip_bf16.h>

#define NNODES 50000
#define NEDGES 800000
#define NGRAPH 128
#define EPSV 1e-5f

// ------------------------------------------------------------------ small prep
__global__ void deg_kernel(const int* __restrict__ src, const int* __restrict__ dst,
                           int* __restrict__ outdeg, int* __restrict__ indeg, int E) {
    int e = blockIdx.x * blockDim.x + threadIdx.x;
    if (e < E) {
        atomicAdd(&outdeg[src[e]], 1);
        atomicAdd(&indeg[dst[e]], 1);
    }
}

__global__ void dinv_kernel(const int* __restrict__ outdeg, float* __restrict__ dinv, int n) {
    int i = blockIdx.x * blockDim.x + threadIdx.x;
    if (i < n) {
        int d = outdeg[i];
        dinv[i] = (d > 0) ? rsqrtf((float)d) : 0.0f;
    }
}

// single-block exclusive scan of indeg -> row_off (N=50000, 49 chunks of 1024)
__global__ void scan_kernel(const int* __restrict__ deg, int* __restrict__ row_off, int n) {
    __shared__ int sdata[1024];
    __shared__ int s_run;
    int t = threadIdx.x;
    if (t == 0) s_run = 0;
    __syncthreads();
    for (int base = 0; base < n; base += 1024) {
        int v = (base + t < n) ? deg[base + t] : 0;
        sdata[t] = v;
        __syncthreads();
        for (int off = 1; off < 1024; off <<= 1) {
            int x = (t >= off) ? sdata[t - off] : 0;
            __syncthreads();
            sdata[t] += x;
            __syncthreads();
        }
        if (base + t < n) row_off[base + t] = s_run + sdata[t] - v;  // exclusive
        __syncthreads();
        if (t == 1023) s_run += sdata[1023];
        __syncthreads();
    }
    if (t == 0) row_off[n] = s_run;
}

__global__ void cursor_copy_kernel(const int* __restrict__ row_off, int* __restrict__ cursor, int n) {
    int i = blockIdx.x * blockDim.x + threadIdx.x;
    if (i < n) cursor[i] = row_off[i];
}

__global__ void fill_kernel(const int* __restrict__ src, const int* __restrict__ dst,
                            int* __restrict__ cursor, int* __restrict__ col, int E) {
    int e = blockIdx.x * blockDim.x + threadIdx.x;
    if (e < E) {
        int d = dst[e];
        int pos = atomicAdd(&cursor[d], 1);
        col[pos] = src[e];
    }
}

// ------------------------------------------------------------------ spmm (wave per node)
// MODE 0: dstv = -dinv_i * sum_j dinv_j * gsrc_j ; cross += sum_j gsrc_i . gsrc_j
// MODE 1: dstv = 2*(-dinv_i * sum) - aux_i                (Cheb tx2)
// MODE 2: cross only
template <int MODE>
__global__ void spmm_kernel(const float* __restrict__ gsrc, const float* __restrict__ aux,
                            float* __restrict__ dstv,
                            const int* __restrict__ row_off, const int* __restrict__ col,
                            const float* __restrict__ dinv, int n,
                            double* __restrict__ cross_acc) {
    int w = (int)((blockIdx.x * (unsigned)blockDim.x + threadIdx.x) >> 6);
    if (w >= n) return;
    int lane = threadIdx.x & 63;
    int s = row_off[w], e = row_off[w + 1];
    float hi0 = 0.f, hi1 = 0.f;
    if (MODE != 1) {
        hi0 = gsrc[(size_t)w * 128 + lane];
        hi1 = gsrc[(size_t)w * 128 + 64 + lane];
    }
    float acc0 = 0.f, acc1 = 0.f, cr = 0.f;
    int p = s;
    int jn = (p < e) ? col[p] : 0;          // 1-ahead index prefetch
    while (p < e) {
        int j = jn;
        ++p;
        jn = (p < e) ? col[p] : 0;
        float dj = dinv[j];
        float v0 = gsrc[(size_t)j * 128 + lane];
        float v1 = gsrc[(size_t)j * 128 + 64 + lane];
        if (MODE != 2) { acc0 += dj * v0; acc1 += dj * v1; }
        if (MODE != 1) { cr += hi0 * v0 + hi1 * v1; }
    }
    if (MODE == 0) {
        float di = dinv[w];
        dstv[(size_t)w * 128 + lane]      = -di * acc0;
        dstv[(size_t)w * 128 + 64 + lane] = -di * acc1;
    } else if (MODE == 1) {
        float di = dinv[w];
        dstv[(size_t)w * 128 + lane]      = -2.f * di * acc0 - aux[(size_t)w * 128 + lane];
        dstv[(size_t)w * 128 + 64 + lane] = -2.f * di * acc1 - aux[(size_t)w * 128 + 64 + lane];
    }
    if (MODE != 1) {
        for (int off = 32; off > 0; off >>= 1) cr += __shfl_down(cr, off, 64);
        if (lane == 0) atomicAdd(cross_acc, (double)cr);
    }
}

// sum_i (outdeg_i+indeg_i)*||h_i||^2  (wave per node)
__global__ void normterm_kernel(const float* __restrict__ h, const int* __restrict__ outdeg,
                                const int* __restrict__ indeg, int n, double* __restrict__ acc) {
    int w = (int)((blockIdx.x * (unsigned)blockDim.x + threadIdx.x) >> 6);
    if (w >= n) return;
    int lane = threadIdx.x & 63;
    float v0 = h[(size_t)w * 128 + lane];
    float v1 = h[(size_t)w * 128 + 64 + lane];
    float ss = v0 * v0 + v1 * v1;
    for (int off = 32; off > 0; off >>= 1) ss += __shfl_down(ss, off, 64);
    if (lane == 0) atomicAdd(acc, (double)ss * (double)(outdeg[w] + indeg[w]));
}

// ------------------------------------------------------------------ GEMM (fp32, 64-row tile)
// out[n][c] = sum_p sum_k Ap[n][k] * Wp[k][c] + bias[c]
// EPI 0: LayerNorm(feature) + ReLU -> outp     (embed)
// EPI 1: raw store -> outp, accumulate per-column sum/sumsq (BN stats)
template <int NPARTS, int EPI>
__global__ __launch_bounds__(256) void gemm_kernel(
    const float* __restrict__ A0, const float* __restrict__ A1, const float* __restrict__ A2,
    const float* __restrict__ W, const float* __restrict__ bias,
    float* __restrict__ outp,
    const float* __restrict__ g0, const float* __restrict__ b0,
    float* __restrict__ colsum, float* __restrict__ colsumsq, int n) {
    __shared__ float As[32][68];      // [k][row] transposed, padded
    __shared__ float Ws[32][128];     // [k][col]
    __shared__ float red1[128];
    __shared__ float red2[128];
    int t = threadIdx.x;
    if (t < 128) { red1[t] = 0.f; red2[t] = 0.f; }
    int rowBase = blockIdx.x * 64;
    int r0 = (t >> 4) * 4;
    int c0 = (t & 15) * 8;
    float acc[4][8];
#pragma unroll
    for (int r = 0; r < 4; ++r)
#pragma unroll
        for (int c = 0; c < 8; ++c) acc[r][c] = 0.f;

    const float* Aparts[3] = {A0, A1, A2};
    for (int part = 0; part < NPARTS; ++part) {
        const float* A = Aparts[part];
        const float* Wp = W + (size_t)part * 128 * 128;
        for (int k0 = 0; k0 < 128; k0 += 32) {
            __syncthreads();
#pragma unroll
            for (int i = 0; i < 2; ++i) {     // stage A 64x32 (transposed)
                int id = t + 256 * i;
                int row = id >> 3;
                int kk = id & 7;
                int gr = rowBase + row;
                float4 a;
                if (gr < n) a = *(const float4*)&A[(size_t)gr * 128 + k0 + kk * 4];
                else a = make_float4(0.f, 0.f, 0.f, 0.f);
                As[kk * 4 + 0][row] = a.x;
                As[kk * 4 + 1][row] = a.y;
                As[kk * 4 + 2][row] = a.z;
                As[kk * 4 + 3][row] = a.w;
            }
#pragma unroll
            for (int i = 0; i < 4; ++i) {     // stage W 32x128
                int id = t + 256 * i;
                int kk = id >> 5;
                int cc = (id & 31) * 4;
                *(float4*)&Ws[kk][cc] = *(const float4*)&Wp[(size_t)(k0 + kk) * 128 + cc];
            }
            __syncthreads();
#pragma unroll
            for (int k = 0; k < 32; ++k) {
                float4 a  = *(const float4*)&As[k][r0];
                float4 w0 = *(const float4*)&Ws[k][c0];
                float4 w1 = *(const float4*)&Ws[k][c0 + 4];
                float av[4] = {a.x, a.y, a.z, a.w};
                float wv[8] = {w0.x, w0.y, w0.z, w0.w, w1.x, w1.y, w1.z, w1.w};
#pragma unroll
                for (int r = 0; r < 4; ++r)
#pragma unroll
                    for (int c = 0; c < 8; ++c) acc[r][c] += av[r] * wv[c];
            }
        }
    }
#pragma unroll
    for (int c = 0; c < 8; ++c) {
        float b = bias[c0 + c];
#pragma unroll
        for (int r = 0; r < 4; ++r) acc[r][c] += b;
    }
    __syncthreads();
    if (EPI == 0) {
        // per-row LayerNorm + ReLU
#pragma unroll
        for (int r = 0; r < 4; ++r) {
            float s = 0.f, ss = 0.f;
#pragma unroll
            for (int c = 0; c < 8; ++c) { s += acc[r][c]; ss += acc[r][c] * acc[r][c]; }
            atomicAdd(&red1[r0 + r], s);
            atomicAdd(&red2[r0 + r], ss);
        }
        __syncthreads();
#pragma unroll
        for (int r = 0; r < 4; ++r) {
            int gr = rowBase + r0 + r;
            if (gr >= n) continue;
            float mean = red1[r0 + r] * (1.f / 128.f);
            float var  = red2[r0 + r] * (1.f / 128.f) - mean * mean;
            float rstd = rsqrtf(var + EPSV);
            float v[8];
#pragma unroll
            for (int c = 0; c < 8; ++c) {
                float x = (acc[r][c] - mean) * rstd * g0[c0 + c] + b0[c0 + c];
                v[c] = fmaxf(x, 0.f);
            }
            *(float4*)&outp[(size_t)gr * 128 + c0]     = make_float4(v[0], v[1], v[2], v[3]);
            *(float4*)&outp[(size_t)gr * 128 + c0 + 4] = make_float4(v[4], v[5], v[6], v[7]);
        }
    } else {
#pragma unroll
        for (int r = 0; r < 4; ++r) {
            int gr = rowBase + r0 + r;
            if (gr >= n) continue;
            *(float4*)&outp[(size_t)gr * 128 + c0]     = make_float4(acc[r][0], acc[r][1], acc[r][2], acc[r][3]);
            *(float4*)&outp[(size_t)gr * 128 + c0 + 4] = make_float4(acc[r][4], acc[r][5], acc[r][6], acc[r][7]);
        }
#pragma unroll
        for (int c = 0; c < 8; ++c) {
            float s = 0.f, ss = 0.f;
#pragma unroll
            for (int r = 0; r < 4; ++r) {
                int gr = rowBase + r0 + r;
                if (gr < n) { s += acc[r][c]; ss += acc[r][c] * acc[r][c]; }
            }
            atomicAdd(&red1[c0 + c], s);
            atomicAdd(&red2[c0 + c], ss);
        }
        __syncthreads();
        if (t < 128) {
            atomicAdd(&colsum[t], red1[t]);
            atomicAdd(&colsumsq[t], red2[t]);
        }
    }
}

// ------------------------------------------------------------------ BN apply
__global__ void bnscale_kernel(const float* __restrict__ colsum, const float* __restrict__ colsumsq,
                               const float* __restrict__ bn_g, const float* __restrict__ bn_b,
                               float* __restrict__ ss, int n) {
    int c = threadIdx.x;
    if (c < 128) {
        float m = colsum[c] / (float)n;
        float v = colsumsq[c] / (float)n - m * m;
        float sc = bn_g[c] * rsqrtf(v + EPSV);
        ss[c] = sc;
        ss[128 + c] = bn_b[c] - m * sc;
    }
}

__global__ void bnrelu_kernel(const float* __restrict__ outv, const float* __restrict__ ss,
                              float* __restrict__ h, int total4) {
    int i = blockIdx.x * blockDim.x + threadIdx.x;
    if (i >= total4) return;
    float4 o = ((const float4*)outv)[i];
    int c = (i * 4) & 127;
    float4 sc = *(const float4*)&ss[c];
    float4 sh = *(const float4*)&ss[128 + c];
    float4 r;
    r.x = fmaxf(o.x * sc.x + sh.x, 0.f);
    r.y = fmaxf(o.y * sc.y + sh.y, 0.f);
    r.z = fmaxf(o.z * sc.z + sh.z, 0.f);
    r.w = fmaxf(o.w * sc.w + sh.w, 0.f);
    ((float4*)h)[i] = r;
}

// ------------------------------------------------------------------ pooling + MLP
__global__ void counts_kernel(const int* __restrict__ batch, int* __restrict__ counts, int n) {
    int i = blockIdx.x * blockDim.x + threadIdx.x;
    if (i < n) atomicAdd(&counts[batch[i]], 1);
}

__global__ void pool_kernel(const float* __restrict__ h, const int* __restrict__ batch,
                            float* __restrict__ gsum, int n) {
    int c = threadIdx.x;               // 128 threads = feature dim
    int r0 = blockIdx.x * 256;
    int r1 = min(r0 + 256, n);
    int cur = -1;
    float acc = 0.f;
    for (int r = r0; r < r1; ++r) {
        int g = batch[r];              // sorted -> rare flushes
        if (g != cur) {
            if (cur >= 0) atomicAdd(&gsum[(size_t)cur * 128 + c], acc);
            cur = g; acc = 0.f;
        }
        acc += h[(size_t)r * 128 + c];
    }
    if (cur >= 0) atomicAdd(&gsum[(size_t)cur * 128 + c], acc);
}

__global__ void mlp_kernel(const float* __restrict__ gsum, const int* __restrict__ counts,
                           const float* __restrict__ w1, const float* __restrict__ b1,
                           const float* __restrict__ w2, const float* __restrict__ b2,
                           const double* __restrict__ accums, float* __restrict__ out) {
    __shared__ float gm[128];
    int g = blockIdx.x;
    int t = threadIdx.x;               // 64 threads
    float cnt = fmaxf((float)counts[g], 1.f);
    gm[t]      = gsum[(size_t)g * 128 + t] / cnt;
    gm[t + 64] = gsum[(size_t)g * 128 + 64 + t] / cnt;
    __syncthreads();
    float z = b1[t];
    for (int k = 0; k < 128; ++k) z += gm[k] * w1[(size_t)k * 64 + t];
    z = fmaxf(z, 0.f);
    float p0 = z * w2[t * 2 + 0];
    float p1 = z * w2[t * 2 + 1];
    for (int off = 32; off > 0; off >>= 1) {
        p0 += __shfl_down(p0, off, 64);
        p1 += __shfl_down(p1, off, 64);
    }
    if (t == 0) {
        out[g * 2 + 0] = p0 + b2[0];
        out[g * 2 + 1] = p1 + b2[1];
        if (g == 0) {
            double reg = (accums[0] - 2.0 * accums[1]) / ((double)NEDGES * 4.0);
            out[256] = (float)reg;
        }
    }
}

// ------------------------------------------------------------------ launch
extern "C" void kernel_launch(void* const* d_in, const int* in_sizes, int n_in,
                              void* d_out, int out_size, void* d_ws, size_t ws_size,
                              hipStream_t stream) {
    const float* x      = (const float*)d_in[0];
    const float* w_in   = (const float*)d_in[1];
    const float* b_in   = (const float*)d_in[2];
    const float* ln_g   = (const float*)d_in[3];
    const float* ln_b   = (const float*)d_in[4];
    const float* cheb_w = (const float*)d_in[5];
    const float* cheb_b = (const float*)d_in[6];
    const float* bn_g   = (const float*)d_in[7];
    const float* bn_b   = (const float*)d_in[8];
    const float* w1     = (const float*)d_in[9];
    const float* b1     = (const float*)d_in[10];
    const float* w2     = (const float*)d_in[11];
    const float* b2     = (const float*)d_in[12];
    const int*   eidx   = (const int*)d_in[13];
    const int*   batch  = (const int*)d_in[14];
    const int* src = eidx;
    const int* dst = eidx + NEDGES;
    float* out = (float*)d_out;

    char* ws = (char*)d_ws;
    size_t off = 0;
    auto alloc = [&](size_t bytes) -> void* {
        void* p = ws + off;
        off = (off + bytes + 255) & ~(size_t)255;
        return p;
    };
    float* h   = (float*)alloc((size_t)NNODES * 128 * 4);
    float* t1  = (float*)alloc((size_t)NNODES * 128 * 4);
    float* t2  = (float*)alloc((size_t)NNODES * 128 * 4);
    float* ob  = (float*)alloc((size_t)NNODES * 128 * 4);
    int* outdeg   = (int*)alloc((size_t)NNODES * 4);
    int* indeg    = (int*)alloc((size_t)NNODES * 4);
    float* dinv   = (float*)alloc((size_t)NNODES * 4);
    int* row_off  = (int*)alloc((size_t)(NNODES + 1) * 4);
    int* cursor   = (int*)alloc((size_t)NNODES * 4);
    int* colv     = (int*)alloc((size_t)NEDGES * 4);
    float* colstats = (float*)alloc(256 * 4);      // colsum[128] | colsumsq[128]
    float* ssbuf    = (float*)alloc(256 * 4);      // scale[128]  | shift[128]
    double* accums  = (double*)alloc(2 * 8);       // [0]=norm, [1]=cross
    float* gsum   = (float*)alloc((size_t)NGRAPH * 128 * 4);
    int* counts   = (int*)alloc((size_t)NGRAPH * 4);
    float* colsum = colstats, *colsumsq = colstats + 128;

    hipMemsetAsync(outdeg, 0, (size_t)NNODES * 4, stream);
    hipMemsetAsync(indeg, 0, (size_t)NNODES * 4, stream);
    hipMemsetAsync(accums, 0, 16, stream);
    hipMemsetAsync(gsum, 0, (size_t)NGRAPH * 128 * 4, stream);
    hipMemsetAsync(counts, 0, (size_t)NGRAPH * 4, stream);

    int tE = (NEDGES + 255) / 256;
    int tN = (NNODES + 255) / 256;
    deg_kernel<<<tE, 256, 0, stream>>>(src, dst, outdeg, indeg, NEDGES);
    dinv_kernel<<<tN, 256, 0, stream>>>(outdeg, dinv, NNODES);
    scan_kernel<<<1, 1024, 0, stream>>>(indeg, row_off, NNODES);
    cursor_copy_kernel<<<tN, 256, 0, stream>>>(row_off, cursor, NNODES);
    fill_kernel<<<tE, 256, 0, stream>>>(src, dst, cursor, colv, NEDGES);

    int gemmBlocks = (NNODES + 63) / 64;
    int waveBlocks = (NNODES * 64 + 255) / 256;

    // embed: h0 = ReLU(LN(x @ w_in + b_in))
    gemm_kernel<1, 0><<<gemmBlocks, 256, 0, stream>>>(x, nullptr, nullptr, w_in, b_in, h,
                                                      ln_g, ln_b, nullptr, nullptr, NNODES);
    normterm_kernel<<<waveBlocks, 256, 0, stream>>>(h, outdeg, indeg, NNODES, &accums[0]);

    for (int l = 0; l < 3; ++l) {
        hipMemsetAsync(colstats, 0, 256 * 4, stream);
        // t1 = spmm(h), cross(h) fused
        spmm_kernel<0><<<waveBlocks, 256, 0, stream>>>(h, nullptr, t1, row_off, colv, dinv,
                                                       NNODES, &accums[1]);
        // t2 = 2*spmm(t1) - h
        spmm_kernel<1><<<waveBlocks, 256, 0, stream>>>(t1, h, t2, row_off, colv, dinv,
                                                       NNODES, nullptr);
        // ob = h@W0 + t1@W1 + t2@W2 + b ; accumulate BN column stats
        gemm_kernel<3, 1><<<gemmBlocks, 256, 0, stream>>>(h, t1, t2,
            cheb_w + (size_t)l * 3 * 128 * 128, cheb_b + (size_t)l * 128, ob,
            nullptr, nullptr, colsum, colsumsq, NNODES);
        bnscale_kernel<<<1, 128, 0, stream>>>(colsum, colsumsq, bn_g + (size_t)l * 128,
                                              bn_b + (size_t)l * 128, ssbuf, NNODES);
        int total4 = NNODES * 128 / 4;
        bnrelu_kernel<<<(total4 + 255) / 256, 256, 0, stream>>>(ob, ssbuf, h, total4);
        normterm_kernel<<<waveBlocks, 256, 0, stream>>>(h, outdeg, indeg, NNODES, &accums[0]);
    }
    // final hidden's cross term (no spmm output needed)
    spmm_kernel<2><<<waveBlocks, 256, 0, stream>>>(h, nullptr, nullptr, row_off, colv, dinv,
                                                   NNODES, &accums[1]);

    counts_kernel<<<tN, 256, 0, stream>>>(batch, counts, NNODES);
    pool_kernel<<<(NNODES + 255) / 256, 128, 0, stream>>>(h, batch, gsum, NNODES);
    mlp_kernel<<<NGRAPH, 64, 0, stream>>>(gsum, counts, w1, b1, w2, b2, accums, out);
}

// Round 2
// 1470.244 us; speedup vs baseline: 4.1014x; 4.1014x over previous
//
#include <hip/hip_runtime.h>
#include <hip/hip_bf16.h>

#define NNODES 50000
#define NEDGES 800000
#define NGRAPH 128
#define EPSV 1e-5f

// ------------------------------------------------------------------ small prep
__global__ void deg_kernel(const int* __restrict__ src, const int* __restrict__ dst,
                           int* __restrict__ outdeg, int* __restrict__ indeg, int E) {
    int e = blockIdx.x * blockDim.x + threadIdx.x;
    if (e < E) {
        atomicAdd(&outdeg[src[e]], 1);
        atomicAdd(&indeg[dst[e]], 1);
    }
}

__global__ void dinv_kernel(const int* __restrict__ outdeg, float* __restrict__ dinv, int n) {
    int i = blockIdx.x * blockDim.x + threadIdx.x;
    if (i < n) {
        int d = outdeg[i];
        dinv[i] = (d > 0) ? rsqrtf((float)d) : 0.0f;
    }
}

// single-block exclusive scan: each thread owns a contiguous chunk, 2 passes over deg
__global__ void scan_kernel(const int* __restrict__ deg, int* __restrict__ row_off, int n) {
    const int TPB = 1024;
    __shared__ int sh[TPB];
    int t = threadIdx.x;
    int per = (n + TPB - 1) / TPB;
    int s0 = t * per, s1 = min(s0 + per, n);
    int sum = 0;
    for (int i = s0; i < s1; ++i) sum += deg[i];
    sh[t] = sum;
    __syncthreads();
    for (int off = 1; off < TPB; off <<= 1) {
        int x = (t >= off) ? sh[t - off] : 0;
        __syncthreads();
        sh[t] += x;
        __syncthreads();
    }
    int run = sh[t] - sum;   // exclusive prefix of this thread's chunk
    for (int i = s0; i < s1; ++i) { row_off[i] = run; run += deg[i]; }
    if (t == TPB - 1) row_off[n] = sh[t];
}

__global__ void cursor_copy_kernel(const int* __restrict__ row_off, int* __restrict__ cursor, int n) {
    int i = blockIdx.x * blockDim.x + threadIdx.x;
    if (i < n) cursor[i] = row_off[i];
}

__global__ void fill_kernel(const int* __restrict__ src, const int* __restrict__ dst,
                            int* __restrict__ cursor, int* __restrict__ col, int E) {
    int e = blockIdx.x * blockDim.x + threadIdx.x;
    if (e < E) {
        int d = dst[e];
        int pos = atomicAdd(&cursor[d], 1);
        col[pos] = src[e];
    }
}

// ------------------------------------------------------------------ spmm (wave per node, float4, 8 rows in flight)
// MODE 0: dstv = -dinv_i * sum_j dinv_j h_j ; cross += h_i.h_j ; norm += (od+id)*||h_i||^2
// MODE 1: dstv = 2*(-dinv_i * sum) - aux_i
// MODE 2: cross + norm only
template <int MODE>
__global__ void spmm_kernel(const float* __restrict__ gsrc, const float* __restrict__ aux,
                            float* __restrict__ dstv,
                            const int* __restrict__ row_off, const int* __restrict__ col,
                            const float* __restrict__ dinv,
                            const int* __restrict__ outdeg, const int* __restrict__ indeg,
                            int n, double* __restrict__ norm_slots, double* __restrict__ cross_slots) {
    int w = (int)((blockIdx.x * (unsigned)blockDim.x + threadIdx.x) >> 6);
    if (w >= n) return;
    int lane = threadIdx.x & 63;
    int g = lane >> 5;          // neighbor slot group (0/1)
    int q = lane & 31;          // float4 column index (covers 128 cols)
    int s = row_off[w], e = row_off[w + 1];
    float4 hi = make_float4(0.f, 0.f, 0.f, 0.f);
    if (MODE != 1) hi = *(const float4*)&gsrc[(size_t)w * 128 + q * 4];
    float4 acc = make_float4(0.f, 0.f, 0.f, 0.f);
    float cr = 0.f;
    for (int base = s; base < e; base += 64) {
        int mm = min(e - base, 64);
        int idx = 0; float dv = 0.f;
        if (lane < mm) { idx = col[base + lane]; dv = dinv[idx]; }
        int iters = (mm + 7) >> 3;          // 8 neighbors per iteration (4 per group)
        for (int it = 0; it < iters; ++it) {
            int sb = (it << 3) + (g << 2);  // this group's first slot
            int j0 = __shfl(idx, sb + 0, 64); float d0 = __shfl(dv, sb + 0, 64);
            int j1 = __shfl(idx, sb + 1, 64); float d1 = __shfl(dv, sb + 1, 64);
            int j2 = __shfl(idx, sb + 2, 64); float d2 = __shfl(dv, sb + 2, 64);
            int j3 = __shfl(idx, sb + 3, 64); float d3 = __shfl(dv, sb + 3, 64);
            float4 v0 = make_float4(0.f,0.f,0.f,0.f), v1 = v0, v2 = v0, v3 = v0;
            if (sb + 0 < mm) v0 = *(const float4*)&gsrc[(size_t)j0 * 128 + q * 4];
            if (sb + 1 < mm) v1 = *(const float4*)&gsrc[(size_t)j1 * 128 + q * 4];
            if (sb + 2 < mm) v2 = *(const float4*)&gsrc[(size_t)j2 * 128 + q * 4];
            if (sb + 3 < mm) v3 = *(const float4*)&gsrc[(size_t)j3 * 128 + q * 4];
            if (MODE != 2) {
                acc.x += d0*v0.x + d1*v1.x + d2*v2.x + d3*v3.x;
                acc.y += d0*v0.y + d1*v1.y + d2*v2.y + d3*v3.y;
                acc.z += d0*v0.z + d1*v1.z + d2*v2.z + d3*v3.z;
                acc.w += d0*v0.w + d1*v1.w + d2*v2.w + d3*v3.w;
            }
            if (MODE != 1) {
                cr += hi.x*(v0.x+v1.x+v2.x+v3.x);   // NO - must be per-neighbor weighted? cross is unweighted sum of dots
                cr += hi.y*(v0.y+v1.y+v2.y+v3.y);
                cr += hi.z*(v0.z+v1.z+v2.z+v3.z);
                cr += hi.w*(v0.w+v1.w+v2.w+v3.w);
            }
        }
    }
    if (MODE != 2) {
        // combine the two neighbor groups (same q columns)
        acc.x += __shfl_xor(acc.x, 32, 64);
        acc.y += __shfl_xor(acc.y, 32, 64);
        acc.z += __shfl_xor(acc.z, 32, 64);
        acc.w += __shfl_xor(acc.w, 32, 64);
        if (g == 0) {
            float di = dinv[w];
            float4 r;
            if (MODE == 0) {
                r.x = -di * acc.x; r.y = -di * acc.y; r.z = -di * acc.z; r.w = -di * acc.w;
            } else {
                float4 ax = *(const float4*)&aux[(size_t)w * 128 + q * 4];
                r.x = -2.f * di * acc.x - ax.x;
                r.y = -2.f * di * acc.y - ax.y;
                r.z = -2.f * di * acc.z - ax.z;
                r.w = -2.f * di * acc.w - ax.w;
            }
            *(float4*)&dstv[(size_t)w * 128 + q * 4] = r;
        }
    }
    if (MODE != 1) {
        float nt = 0.5f * (hi.x*hi.x + hi.y*hi.y + hi.z*hi.z + hi.w*hi.w); // both groups hold same cols
        for (int off = 32; off > 0; off >>= 1) {
            cr += __shfl_down(cr, off, 64);
            nt += __shfl_down(nt, off, 64);
        }
        if (lane == 0) {
            int slot = w & 255;
            atomicAdd(&cross_slots[slot], (double)cr);
            atomicAdd(&norm_slots[slot], (double)nt * (double)(outdeg[w] + indeg[w]));
        }
    }
}

// ------------------------------------------------------------------ GEMM (fp32, 64-row tile, reg-prefetch pipeline)
// out[n][c] = sum_p sum_k Ap[n][k] * Wp[k][c] + bias[c]
// EPI 0: LayerNorm(feature) + ReLU -> outp     (embed)
// EPI 1: raw store -> outp, accumulate per-column sum/sumsq (BN stats)
template <int NPARTS, int EPI>
__global__ __launch_bounds__(256) void gemm_kernel(
    const float* __restrict__ A0, const float* __restrict__ A1, const float* __restrict__ A2,
    const float* __restrict__ W, const float* __restrict__ bias,
    float* __restrict__ outp,
    const float* __restrict__ g0, const float* __restrict__ b0,
    float* __restrict__ colsum, float* __restrict__ colsumsq, int n) {
    __shared__ float As[64][36];       // [row][k] padded to 36 -> conflict-free float4 staging
    __shared__ float Ws[32][128];      // [k][col]
    __shared__ float red1[128];
    __shared__ float red2[128];
    int t = threadIdx.x;
    if (t < 128) { red1[t] = 0.f; red2[t] = 0.f; }
    int rowBase = blockIdx.x * 64;
    int r0 = (t >> 4) * 4;
    int cA = (t & 15) * 4, cB = cA + 64;   // two conflict-free float4 column groups
    float acc[4][8];
#pragma unroll
    for (int r = 0; r < 4; ++r)
#pragma unroll
        for (int c = 0; c < 8; ++c) acc[r][c] = 0.f;

    const float* Aparts[3] = {A0, A1, A2};
    int aRow = t >> 3;                 // 0..31 (+32 for i=1)
    int aK   = (t & 7) * 4;
    int wK   = t >> 5;                 // 0..7  (+8*i)
    int wC   = (t & 31) * 4;
    float4 aR[2], wR[4];
    const int T = NPARTS * 4;

    auto load_tile = [&](int tile) {
        int part = tile >> 2;
        int k0 = (tile & 3) * 32;
        const float* A = Aparts[part];
        const float* Wp = W + (size_t)part * 16384;
#pragma unroll
        for (int i = 0; i < 2; ++i) {
            int gr = rowBase + aRow + i * 32;
            aR[i] = (gr < n) ? *(const float4*)&A[(size_t)gr * 128 + k0 + aK]
                             : make_float4(0.f, 0.f, 0.f, 0.f);
        }
#pragma unroll
        for (int i = 0; i < 4; ++i)
            wR[i] = *(const float4*)&Wp[(size_t)(k0 + wK + i * 8) * 128 + wC];
    };

    load_tile(0);
    for (int tile = 0; tile < T; ++tile) {
        __syncthreads();
#pragma unroll
        for (int i = 0; i < 2; ++i)
            *(float4*)&As[aRow + i * 32][aK] = aR[i];
#pragma unroll
        for (int i = 0; i < 4; ++i)
            *(float4*)&Ws[wK + i * 8][wC] = wR[i];
        __syncthreads();
        if (tile + 1 < T) load_tile(tile + 1);   // issue next tile's global loads early
#pragma unroll
        for (int k = 0; k < 32; k += 4) {
            float4 a4[4];
#pragma unroll
            for (int r = 0; r < 4; ++r) a4[r] = *(const float4*)&As[r0 + r][k];
#pragma unroll
            for (int kk = 0; kk < 4; ++kk) {
                float4 w0 = *(const float4*)&Ws[k + kk][cA];
                float4 w1 = *(const float4*)&Ws[k + kk][cB];
                float wv[8] = {w0.x, w0.y, w0.z, w0.w, w1.x, w1.y, w1.z, w1.w};
#pragma unroll
                for (int r = 0; r < 4; ++r) {
                    float ar = ((const float*)&a4[r])[kk];
#pragma unroll
                    for (int c = 0; c < 8; ++c) acc[r][c] += ar * wv[c];
                }
            }
        }
    }
#pragma unroll
    for (int c = 0; c < 8; ++c) {
        int cc = (c < 4) ? (cA + c) : (cB + c - 4);
        float b = bias[cc];
#pragma unroll
        for (int r = 0; r < 4; ++r) acc[r][c] += b;
    }
    __syncthreads();
    if (EPI == 0) {
        // per-row LayerNorm + ReLU
#pragma unroll
        for (int r = 0; r < 4; ++r) {
            float s = 0.f, ss = 0.f;
#pragma unroll
            for (int c = 0; c < 8; ++c) { s += acc[r][c]; ss += acc[r][c] * acc[r][c]; }
            atomicAdd(&red1[r0 + r], s);
            atomicAdd(&red2[r0 + r], ss);
        }
        __syncthreads();
#pragma unroll
        for (int r = 0; r < 4; ++r) {
            int gr = rowBase + r0 + r;
            if (gr >= n) continue;
            float mean = red1[r0 + r] * (1.f / 128.f);
            float var  = red2[r0 + r] * (1.f / 128.f) - mean * mean;
            float rstd = rsqrtf(var + EPSV);
            float v[8];
#pragma unroll
            for (int c = 0; c < 8; ++c) {
                int cc = (c < 4) ? (cA + c) : (cB + c - 4);
                float x = (acc[r][c] - mean) * rstd * g0[cc] + b0[cc];
                v[c] = fmaxf(x, 0.f);
            }
            *(float4*)&outp[(size_t)gr * 128 + cA] = make_float4(v[0], v[1], v[2], v[3]);
            *(float4*)&outp[(size_t)gr * 128 + cB] = make_float4(v[4], v[5], v[6], v[7]);
        }
    } else {
#pragma unroll
        for (int r = 0; r < 4; ++r) {
            int gr = rowBase + r0 + r;
            if (gr >= n) continue;
            *(float4*)&outp[(size_t)gr * 128 + cA] = make_float4(acc[r][0], acc[r][1], acc[r][2], acc[r][3]);
            *(float4*)&outp[(size_t)gr * 128 + cB] = make_float4(acc[r][4], acc[r][5], acc[r][6], acc[r][7]);
        }
#pragma unroll
        for (int c = 0; c < 8; ++c) {
            int cc = (c < 4) ? (cA + c) : (cB + c - 4);
            float s = 0.f, ss = 0.f;
#pragma unroll
            for (int r = 0; r < 4; ++r) {
                int gr = rowBase + r0 + r;
                if (gr < n) { s += acc[r][c]; ss += acc[r][c] * acc[r][c]; }
            }
            atomicAdd(&red1[cc], s);
            atomicAdd(&red2[cc], ss);
        }
        __syncthreads();
        if (t < 128) {
            atomicAdd(&colsum[t], red1[t]);
            atomicAdd(&colsumsq[t], red2[t]);
        }
    }
}

// ------------------------------------------------------------------ BN apply
__global__ void bnscale_kernel(const float* __restrict__ colsum, const float* __restrict__ colsumsq,
                               const float* __restrict__ bn_g, const float* __restrict__ bn_b,
                               float* __restrict__ ss, int n) {
    int c = threadIdx.x;
    if (c < 128) {
        float m = colsum[c] / (float)n;
        float v = colsumsq[c] / (float)n - m * m;
        float sc = bn_g[c] * rsqrtf(v + EPSV);
        ss[c] = sc;
        ss[128 + c] = bn_b[c] - m * sc;
    }
}

__global__ void bnrelu_kernel(const float* __restrict__ outv, const float* __restrict__ ss,
                              float* __restrict__ h, int total4) {
    int i = blockIdx.x * blockDim.x + threadIdx.x;
    if (i >= total4) return;
    float4 o = ((const float4*)outv)[i];
    int c = (i * 4) & 127;
    float4 sc = *(const float4*)&ss[c];
    float4 sh = *(const float4*)&ss[128 + c];
    float4 r;
    r.x = fmaxf(o.x * sc.x + sh.x, 0.f);
    r.y = fmaxf(o.y * sc.y + sh.y, 0.f);
    r.z = fmaxf(o.z * sc.z + sh.z, 0.f);
    r.w = fmaxf(o.w * sc.w + sh.w, 0.f);
    ((float4*)h)[i] = r;
}

// ------------------------------------------------------------------ pooling + MLP
__global__ void counts_kernel(const int* __restrict__ batch, int* __restrict__ counts, int n) {
    int i = blockIdx.x * blockDim.x + threadIdx.x;
    if (i < n) atomicAdd(&counts[batch[i]], 1);
}

__global__ void pool_kernel(const float* __restrict__ h, const int* __restrict__ batch,
                            float* __restrict__ gsum, int n) {
    int c = threadIdx.x;               // 128 threads = feature dim
    int r0 = blockIdx.x * 256;
    int r1 = min(r0 + 256, n);
    int cur = -1;
    float acc = 0.f;
    for (int r = r0; r < r1; ++r) {
        int g = batch[r];              // sorted -> rare flushes
        if (g != cur) {
            if (cur >= 0) atomicAdd(&gsum[(size_t)cur * 128 + c], acc);
            cur = g; acc = 0.f;
        }
        acc += h[(size_t)r * 128 + c];
    }
    if (cur >= 0) atomicAdd(&gsum[(size_t)cur * 128 + c], acc);
}

__global__ void mlp_kernel(const float* __restrict__ gsum, const int* __restrict__ counts,
                           const float* __restrict__ w1, const float* __restrict__ b1,
                           const float* __restrict__ w2, const float* __restrict__ b2,
                           const double* __restrict__ norm_slots, const double* __restrict__ cross_slots,
                           float* __restrict__ out) {
    __shared__ float gm[128];
    int g = blockIdx.x;
    int t = threadIdx.x;               // 64 threads
    float cnt = fmaxf((float)counts[g], 1.f);
    gm[t]      = gsum[(size_t)g * 128 + t] / cnt;
    gm[t + 64] = gsum[(size_t)g * 128 + 64 + t] / cnt;
    __syncthreads();
    float z = b1[t];
    for (int k = 0; k < 128; ++k) z += gm[k] * w1[(size_t)k * 64 + t];
    z = fmaxf(z, 0.f);
    float p0 = z * w2[t * 2 + 0];
    float p1 = z * w2[t * 2 + 1];
    for (int off = 32; off > 0; off >>= 1) {
        p0 += __shfl_down(p0, off, 64);
        p1 += __shfl_down(p1, off, 64);
    }
    if (t == 0) {
        out[g * 2 + 0] = p0 + b2[0];
        out[g * 2 + 1] = p1 + b2[1];
    }
    if (g == 0) {
        double ns = 0.0, cs = 0.0;
        for (int i = t; i < 256; i += 64) { ns += norm_slots[i]; cs += cross_slots[i]; }
        for (int off = 32; off > 0; off >>= 1) {
            ns += __shfl_down(ns, off, 64);
            cs += __shfl_down(cs, off, 64);
        }
        if (t == 0) out[256] = (float)((ns - 2.0 * cs) / ((double)NEDGES * 4.0));
    }
}

// ------------------------------------------------------------------ launch
extern "C" void kernel_launch(void* const* d_in, const int* in_sizes, int n_in,
                              void* d_out, int out_size, void* d_ws, size_t ws_size,
                              hipStream_t stream) {
    const float* x      = (const float*)d_in[0];
    const float* w_in   = (const float*)d_in[1];
    const float* b_in   = (const float*)d_in[2];
    const float* ln_g   = (const float*)d_in[3];
    const float* ln_b   = (const float*)d_in[4];
    const float* cheb_w = (const float*)d_in[5];
    const float* cheb_b = (const float*)d_in[6];
    const float* bn_g   = (const float*)d_in[7];
    const float* bn_b   = (const float*)d_in[8];
    const float* w1     = (const float*)d_in[9];
    const float* b1     = (const float*)d_in[10];
    const float* w2     = (const float*)d_in[11];
    const float* b2     = (const float*)d_in[12];
    const int*   eidx   = (const int*)d_in[13];
    const int*   batch  = (const int*)d_in[14];
    const int* src = eidx;
    const int* dst = eidx + NEDGES;
    float* out = (float*)d_out;

    char* ws = (char*)d_ws;
    size_t off = 0;
    auto alloc = [&](size_t bytes) -> void* {
        void* p = ws + off;
        off = (off + bytes + 255) & ~(size_t)255;
        return p;
    };
    float* h   = (float*)alloc((size_t)NNODES * 128 * 4);
    float* t1  = (float*)alloc((size_t)NNODES * 128 * 4);
    float* t2  = (float*)alloc((size_t)NNODES * 128 * 4);
    float* ob  = (float*)alloc((size_t)NNODES * 128 * 4);
    int* outdeg   = (int*)alloc((size_t)NNODES * 4);
    int* indeg    = (int*)alloc((size_t)NNODES * 4);
    float* dinv   = (float*)alloc((size_t)NNODES * 4);
    int* row_off  = (int*)alloc((size_t)(NNODES + 1) * 4);
    int* cursor   = (int*)alloc((size_t)NNODES * 4);
    int* colv     = (int*)alloc((size_t)NEDGES * 4);
    float* colstats = (float*)alloc(256 * 4);        // colsum[128] | colsumsq[128]
    float* ssbuf    = (float*)alloc(256 * 4);        // scale[128]  | shift[128]
    double* norm_slots  = (double*)alloc(256 * 8);
    double* cross_slots = (double*)alloc(256 * 8);
    float* gsum   = (float*)alloc((size_t)NGRAPH * 128 * 4);
    int* counts   = (int*)alloc((size_t)NGRAPH * 4);
    float* colsum = colstats, *colsumsq = colstats + 128;

    hipMemsetAsync(outdeg, 0, (size_t)NNODES * 4, stream);
    hipMemsetAsync(indeg, 0, (size_t)NNODES * 4, stream);
    hipMemsetAsync(norm_slots, 0, 256 * 8, stream);
    hipMemsetAsync(cross_slots, 0, 256 * 8, stream);
    hipMemsetAsync(gsum, 0, (size_t)NGRAPH * 128 * 4, stream);
    hipMemsetAsync(counts, 0, (size_t)NGRAPH * 4, stream);

    int tE = (NEDGES + 255) / 256;
    int tN = (NNODES + 255) / 256;
    deg_kernel<<<tE, 256, 0, stream>>>(src, dst, outdeg, indeg, NEDGES);
    dinv_kernel<<<tN, 256, 0, stream>>>(outdeg, dinv, NNODES);
    scan_kernel<<<1, 1024, 0, stream>>>(indeg, row_off, NNODES);
    cursor_copy_kernel<<<tN, 256, 0, stream>>>(row_off, cursor, NNODES);
    fill_kernel<<<tE, 256, 0, stream>>>(src, dst, cursor, colv, NEDGES);

    int gemmBlocks = (NNODES + 63) / 64;
    int waveBlocks = (NNODES * 64 + 255) / 256;

    // embed: h0 = ReLU(LN(x @ w_in + b_in))
    gemm_kernel<1, 0><<<gemmBlocks, 256, 0, stream>>>(x, nullptr, nullptr, w_in, b_in, h,
                                                      ln_g, ln_b, nullptr, nullptr, NNODES);

    for (int l = 0; l < 3; ++l) {
        hipMemsetAsync(colstats, 0, 256 * 4, stream);
        // t1 = spmm(h); fused: cross(h), norm(h)
        spmm_kernel<0><<<waveBlocks, 256, 0, stream>>>(h, nullptr, t1, row_off, colv, dinv,
                                                       outdeg, indeg, NNODES, norm_slots, cross_slots);
        // t2 = 2*spmm(t1) - h
        spmm_kernel<1><<<waveBlocks, 256, 0, stream>>>(t1, h, t2, row_off, colv, dinv,
                                                       outdeg, indeg, NNODES, nullptr, nullptr);
        // ob = h@W0 + t1@W1 + t2@W2 + b ; accumulate BN column stats
        gemm_kernel<3, 1><<<gemmBlocks, 256, 0, stream>>>(h, t1, t2,
            cheb_w + (size_t)l * 3 * 128 * 128, cheb_b + (size_t)l * 128, ob,
            nullptr, nullptr, colsum, colsumsq, NNODES);
        bnscale_kernel<<<1, 128, 0, stream>>>(colsum, colsumsq, bn_g + (size_t)l * 128,
                                              bn_b + (size_t)l * 128, ssbuf, NNODES);
        int total4 = NNODES * 128 / 4;
        bnrelu_kernel<<<(total4 + 255) / 256, 256, 0, stream>>>(ob, ssbuf, h, total4);
    }
    // final hidden's cross + norm terms
    spmm_kernel<2><<<waveBlocks, 256, 0, stream>>>(h, nullptr, nullptr, row_off, colv, dinv,
                                                   outdeg, indeg, NNODES, norm_slots, cross_slots);

    counts_kernel<<<tN, 256, 0, stream>>>(batch, counts, NNODES);
    pool_kernel<<<(NNODES + 255) / 256, 128, 0, stream>>>(h, batch, gsum, NNODES);
    mlp_kernel<<<NGRAPH, 64, 0, stream>>>(gsum, counts, w1, b1, w2, b2,
                                          norm_slots, cross_slots, out);
}

// Round 3
// 1115.695 us; speedup vs baseline: 5.4047x; 1.3178x over previous
//
#include <hip/hip_runtime.h>
#include <hip/hip_bf16.h>

#define NNODES 50000
#define NEDGES 800000
#define NGRAPH 128
#define EPSV 1e-5f

typedef __attribute__((ext_vector_type(8))) short bf16x8;
typedef __attribute__((ext_vector_type(4))) float f32x4;

__device__ __forceinline__ unsigned short f2bf(float f) {
    unsigned u = __float_as_uint(f);
    return (unsigned short)((u + 0x7fffu + ((u >> 16) & 1u)) >> 16);
}
__device__ __forceinline__ float bf2f(unsigned short h) {
    return __uint_as_float(((unsigned)h) << 16);
}

// ------------------------------------------------------------------ small prep
__global__ void deg_kernel(const int* __restrict__ src, const int* __restrict__ dst,
                           int* __restrict__ outdeg, int* __restrict__ indeg, int E) {
    int e = blockIdx.x * blockDim.x + threadIdx.x;
    if (e < E) {
        atomicAdd(&outdeg[src[e]], 1);
        atomicAdd(&indeg[dst[e]], 1);
    }
}

__global__ void dinv_kernel(const int* __restrict__ outdeg, float* __restrict__ dinv, int n) {
    int i = blockIdx.x * blockDim.x + threadIdx.x;
    if (i < n) {
        int d = outdeg[i];
        dinv[i] = (d > 0) ? rsqrtf((float)d) : 0.0f;
    }
}

__global__ void scan_kernel(const int* __restrict__ deg, int* __restrict__ row_off, int n) {
    const int TPB = 1024;
    __shared__ int sh[TPB];
    int t = threadIdx.x;
    int per = (n + TPB - 1) / TPB;
    int s0 = t * per, s1 = min(s0 + per, n);
    int sum = 0;
    for (int i = s0; i < s1; ++i) sum += deg[i];
    sh[t] = sum;
    __syncthreads();
    for (int off = 1; off < TPB; off <<= 1) {
        int x = (t >= off) ? sh[t - off] : 0;
        __syncthreads();
        sh[t] += x;
        __syncthreads();
    }
    int run = sh[t] - sum;
    for (int i = s0; i < s1; ++i) { row_off[i] = run; run += deg[i]; }
    if (t == TPB - 1) row_off[n] = sh[t];
}

__global__ void cursor_copy_kernel(const int* __restrict__ row_off, int* __restrict__ cursor, int n) {
    int i = blockIdx.x * blockDim.x + threadIdx.x;
    if (i < n) cursor[i] = row_off[i];
}

__global__ void fill_kernel(const int* __restrict__ src, const int* __restrict__ dst,
                            int* __restrict__ cursor, int* __restrict__ col, int E) {
    int e = blockIdx.x * blockDim.x + threadIdx.x;
    if (e < E) {
        int d = dst[e];
        int pos = atomicAdd(&cursor[d], 1);
        col[pos] = src[e];
    }
}

// ------------------------------------------------------------------ W prep: split fp32 -> bf16 hi/lo in MFMA lane order
// part 0 = w_in ; part 1+3l+k = cheb (with recurrence folded: W0-W2, W1, 2*W2)
// slot = ((p*4+kc)*8 + ct)*64 + lane, lane = q*16+n ; 16 ushorts per slot (8 hi | 8 lo)
__global__ void wprep_kernel(const float* __restrict__ w_in, const float* __restrict__ cheb_w,
                             unsigned short* __restrict__ Wsp) {
    int p = blockIdx.x;            // 0..9
    int t = threadIdx.x;           // 256
    for (int s8 = 0; s8 < 8; ++s8) {
        int slot = s8 * 256 + t;   // 0..2047
        int kc = slot >> 9, ct = (slot >> 6) & 7, lane = slot & 63;
        int q = lane >> 4, nn = lane & 15;
        unsigned short* o = Wsp + ((size_t)p * 2048 + slot) * 16;
#pragma unroll
        for (int j = 0; j < 8; ++j) {
            int k = kc * 32 + q * 8 + j, c = ct * 16 + nn;
            float v;
            if (p == 0) {
                v = w_in[k * 128 + c];
            } else {
                int pl = (p - 1) / 3, kk = (p - 1) % 3;
                v = cheb_w[((size_t)(pl * 3 + kk) * 128 + k) * 128 + c];
                if (kk == 0) v -= cheb_w[((size_t)(pl * 3 + 2) * 128 + k) * 128 + c];
                else if (kk == 2) v *= 2.f;
            }
            unsigned short hi = f2bf(v);
            o[j] = hi;
            o[8 + j] = f2bf(v - bf2f(hi));
        }
    }
}

// ------------------------------------------------------------------ MFMA GEMM (LDS-free, split bf16)
// out[r][c] = sum_p A_p[r][:] @ W_p + bias ; EPI 0: LayerNorm+ReLU (+bf16 out), EPI 1: store + BN col stats
template <int NPARTS, int EPI>
__global__ __launch_bounds__(256) void gemm_mfma(
    const float* __restrict__ A0, const float* __restrict__ A1, const float* __restrict__ A2,
    const unsigned short* __restrict__ Wsp, const float* __restrict__ bias,
    float* __restrict__ outp, unsigned short* __restrict__ out16,
    const float* __restrict__ g0, const float* __restrict__ b0,
    float* __restrict__ colsum, float* __restrict__ colsumsq, int n) {
    __shared__ float red[256];
    int t = threadIdx.x, w = t >> 6, l = t & 63;
    int m = l & 15, qk = l >> 4;
    int rowA = blockIdx.x * 64 + w * 16 + m;          // row this lane loads (A operand)
    red[t] = 0.f;
    __syncthreads();

    f32x4 acc[8];
#pragma unroll
    for (int ct = 0; ct < 8; ++ct) acc[ct] = (f32x4){0.f, 0.f, 0.f, 0.f};

    const float* Ap[3] = {A0, A1, A2};
    bool valid = rowA < n;
#pragma unroll
    for (int p = 0; p < NPARTS; ++p) {
        const float* arow = Ap[p] + (size_t)rowA * 128;
#pragma unroll
        for (int kc = 0; kc < 4; ++kc) {
            float4 x0, x1;
            if (valid) {
                x0 = *(const float4*)&arow[kc * 32 + qk * 8];
                x1 = *(const float4*)&arow[kc * 32 + qk * 8 + 4];
            } else {
                x0 = make_float4(0.f, 0.f, 0.f, 0.f); x1 = x0;
            }
            float xs[8] = {x0.x, x0.y, x0.z, x0.w, x1.x, x1.y, x1.z, x1.w};
            bf16x8 ah, al;
#pragma unroll
            for (int j = 0; j < 8; ++j) {
                unsigned short hi = f2bf(xs[j]);
                ah[j] = (short)hi;
                al[j] = (short)f2bf(xs[j] - bf2f(hi));
            }
            const unsigned short* wb = Wsp + ((size_t)((p * 4 + kc) * 8) * 64 + l) * 16;
#pragma unroll
            for (int ct = 0; ct < 8; ++ct) {
                bf16x8 bh = *(const bf16x8*)(wb + (size_t)ct * 64 * 16);
                bf16x8 bl = *(const bf16x8*)(wb + (size_t)ct * 64 * 16 + 8);
                acc[ct] = __builtin_amdgcn_mfma_f32_16x16x32_bf16(ah, bh, acc[ct], 0, 0, 0);
                acc[ct] = __builtin_amdgcn_mfma_f32_16x16x32_bf16(al, bh, acc[ct], 0, 0, 0);
                acc[ct] = __builtin_amdgcn_mfma_f32_16x16x32_bf16(ah, bl, acc[ct], 0, 0, 0);
            }
        }
    }

    // C/D layout: col = ct*16 + m, row = blk*64 + w*16 + qk*4 + j
    int rowC0 = blockIdx.x * 64 + w * 16 + qk * 4;
    if (EPI == 0) {
        // LayerNorm over features (row-local) + ReLU, write fp32 + bf16
        float rs[4] = {0.f, 0.f, 0.f, 0.f}, rss[4] = {0.f, 0.f, 0.f, 0.f};
#pragma unroll
        for (int ct = 0; ct < 8; ++ct) {
            float b = bias[ct * 16 + m];
#pragma unroll
            for (int j = 0; j < 4; ++j) {
                float v = acc[ct][j] + b;
                acc[ct][j] = v;
                rs[j] += v; rss[j] += v * v;
            }
        }
#pragma unroll
        for (int off = 1; off < 16; off <<= 1) {
#pragma unroll
            for (int j = 0; j < 4; ++j) {
                rs[j] += __shfl_xor(rs[j], off, 64);
                rss[j] += __shfl_xor(rss[j], off, 64);
            }
        }
        float mean[4], rstd[4];
#pragma unroll
        for (int j = 0; j < 4; ++j) {
            mean[j] = rs[j] * (1.f / 128.f);
            float var = rss[j] * (1.f / 128.f) - mean[j] * mean[j];
            rstd[j] = rsqrtf(var + EPSV);
        }
#pragma unroll
        for (int ct = 0; ct < 8; ++ct) {
            int c = ct * 16 + m;
            float gg = g0[c], bb = b0[c];
#pragma unroll
            for (int j = 0; j < 4; ++j) {
                int gr = rowC0 + j;
                if (gr < n) {
                    float x = (acc[ct][j] - mean[j]) * rstd[j] * gg + bb;
                    x = fmaxf(x, 0.f);
                    outp[(size_t)gr * 128 + c] = x;
                    out16[(size_t)gr * 128 + c] = f2bf(x);
                }
            }
        }
    } else {
        // raw store + BN column stats
#pragma unroll
        for (int ct = 0; ct < 8; ++ct) {
            int c = ct * 16 + m;
            float b = bias[c];
            float s = 0.f, ss = 0.f;
#pragma unroll
            for (int j = 0; j < 4; ++j) {
                int gr = rowC0 + j;
                if (gr < n) {
                    float v = acc[ct][j] + b;
                    outp[(size_t)gr * 128 + c] = v;
                    s += v; ss += v * v;
                }
            }
            s += __shfl_xor(s, 16, 64);  ss += __shfl_xor(ss, 16, 64);
            s += __shfl_xor(s, 32, 64);  ss += __shfl_xor(ss, 32, 64);
            if (qk == 0) {
                atomicAdd(&red[c], s);
                atomicAdd(&red[128 + c], ss);
            }
        }
        __syncthreads();
        if (t < 128) {
            atomicAdd(&colsum[t], red[t]);
            atomicAdd(&colsumsq[t], red[128 + t]);
        }
    }
}

// ------------------------------------------------------------------ spmm (wave per node, bf16 gathers)
// MODE 0: spmm + bf16 out + stats ; MODE 1: spmm only ; MODE 2: stats only
// spmm: dst = -dinv_i * sum_j dinv_j * v_j   (recurrence folded into GEMM weights)
template <int MODE>
__global__ void spmm_kernel(const unsigned short* __restrict__ g16,
                            const float* __restrict__ self32,
                            float* __restrict__ dstv, unsigned short* __restrict__ dst16,
                            const int* __restrict__ row_off, const int* __restrict__ col,
                            const float* __restrict__ dinv,
                            const int* __restrict__ outdeg, const int* __restrict__ indeg,
                            int n, double* __restrict__ norm_slots, double* __restrict__ cross_slots) {
    int w = (int)((blockIdx.x * (unsigned)blockDim.x + threadIdx.x) >> 6);
    if (w >= n) return;
    int lane = threadIdx.x & 63;
    int g = lane >> 5;          // neighbor slot group (0/1)
    int q = lane & 31;          // float4 column index
    int s = row_off[w], e = row_off[w + 1];
    float4 hi = make_float4(0.f, 0.f, 0.f, 0.f);
    if (MODE != 1) hi = *(const float4*)&self32[(size_t)w * 128 + q * 4];
    float4 acc = make_float4(0.f, 0.f, 0.f, 0.f);
    float cr = 0.f;
    for (int base = s; base < e; base += 64) {
        int mm = min(e - base, 64);
        int idx = 0; float dv = 0.f;
        if (lane < mm) { idx = col[base + lane]; dv = dinv[idx]; }
        int iters = (mm + 7) >> 3;
        for (int it = 0; it < iters; ++it) {
            int sb = (it << 3) + (g << 2);
            int j0 = __shfl(idx, sb + 0, 64); float d0 = __shfl(dv, sb + 0, 64);
            int j1 = __shfl(idx, sb + 1, 64); float d1 = __shfl(dv, sb + 1, 64);
            int j2 = __shfl(idx, sb + 2, 64); float d2 = __shfl(dv, sb + 2, 64);
            int j3 = __shfl(idx, sb + 3, 64); float d3 = __shfl(dv, sb + 3, 64);
            ushort4 u0 = make_ushort4(0,0,0,0), u1 = u0, u2 = u0, u3 = u0;
            if (sb + 0 < mm) u0 = *(const ushort4*)&g16[(size_t)j0 * 128 + q * 4];
            if (sb + 1 < mm) u1 = *(const ushort4*)&g16[(size_t)j1 * 128 + q * 4];
            if (sb + 2 < mm) u2 = *(const ushort4*)&g16[(size_t)j2 * 128 + q * 4];
            if (sb + 3 < mm) u3 = *(const ushort4*)&g16[(size_t)j3 * 128 + q * 4];
            float4 v0 = make_float4(bf2f(u0.x), bf2f(u0.y), bf2f(u0.z), bf2f(u0.w));
            float4 v1 = make_float4(bf2f(u1.x), bf2f(u1.y), bf2f(u1.z), bf2f(u1.w));
            float4 v2 = make_float4(bf2f(u2.x), bf2f(u2.y), bf2f(u2.z), bf2f(u2.w));
            float4 v3 = make_float4(bf2f(u3.x), bf2f(u3.y), bf2f(u3.z), bf2f(u3.w));
            if (MODE != 2) {
                acc.x += d0*v0.x + d1*v1.x + d2*v2.x + d3*v3.x;
                acc.y += d0*v0.y + d1*v1.y + d2*v2.y + d3*v3.y;
                acc.z += d0*v0.z + d1*v1.z + d2*v2.z + d3*v3.z;
                acc.w += d0*v0.w + d1*v1.w + d2*v2.w + d3*v3.w;
            }
            if (MODE != 1) {
                cr += hi.x*(v0.x+v1.x+v2.x+v3.x);
                cr += hi.y*(v0.y+v1.y+v2.y+v3.y);
                cr += hi.z*(v0.z+v1.z+v2.z+v3.z);
                cr += hi.w*(v0.w+v1.w+v2.w+v3.w);
            }
        }
    }
    if (MODE != 2) {
        acc.x += __shfl_xor(acc.x, 32, 64);
        acc.y += __shfl_xor(acc.y, 32, 64);
        acc.z += __shfl_xor(acc.z, 32, 64);
        acc.w += __shfl_xor(acc.w, 32, 64);
        if (g == 0) {
            float di = dinv[w];
            float4 r = make_float4(-di * acc.x, -di * acc.y, -di * acc.z, -di * acc.w);
            *(float4*)&dstv[(size_t)w * 128 + q * 4] = r;
            if (MODE == 0) {
                ushort4 u = make_ushort4(f2bf(r.x), f2bf(r.y), f2bf(r.z), f2bf(r.w));
                *(ushort4*)&dst16[(size_t)w * 128 + q * 4] = u;
            }
        }
    }
    if (MODE != 1) {
        float nt = 0.5f * (hi.x*hi.x + hi.y*hi.y + hi.z*hi.z + hi.w*hi.w);
        for (int off = 32; off > 0; off >>= 1) {
            cr += __shfl_down(cr, off, 64);
            nt += __shfl_down(nt, off, 64);
        }
        if (lane == 0) {
            int slot = w & 255;
            atomicAdd(&cross_slots[slot], (double)cr);
            atomicAdd(&norm_slots[slot], (double)nt * (double)(outdeg[w] + indeg[w]));
        }
    }
}

// ------------------------------------------------------------------ BN apply
__global__ void bnscale_kernel(const float* __restrict__ colsum, const float* __restrict__ colsumsq,
                               const float* __restrict__ bn_g, const float* __restrict__ bn_b,
                               float* __restrict__ ss, int n) {
    int c = threadIdx.x;
    if (c < 128) {
        float m = colsum[c] / (float)n;
        float v = colsumsq[c] / (float)n - m * m;
        float sc = bn_g[c] * rsqrtf(v + EPSV);
        ss[c] = sc;
        ss[128 + c] = bn_b[c] - m * sc;
    }
}

__global__ void bnrelu_kernel(const float* __restrict__ outv, const float* __restrict__ ss,
                              float* __restrict__ h, unsigned short* __restrict__ h16, int total4) {
    int i = blockIdx.x * blockDim.x + threadIdx.x;
    if (i >= total4) return;
    float4 o = ((const float4*)outv)[i];
    int c = (i * 4) & 127;
    float4 sc = *(const float4*)&ss[c];
    float4 sh = *(const float4*)&ss[128 + c];
    float4 r;
    r.x = fmaxf(o.x * sc.x + sh.x, 0.f);
    r.y = fmaxf(o.y * sc.y + sh.y, 0.f);
    r.z = fmaxf(o.z * sc.z + sh.z, 0.f);
    r.w = fmaxf(o.w * sc.w + sh.w, 0.f);
    ((float4*)h)[i] = r;
    ushort4 u = make_ushort4(f2bf(r.x), f2bf(r.y), f2bf(r.z), f2bf(r.w));
    ((ushort4*)h16)[i] = u;
}

// ------------------------------------------------------------------ pooling + MLP
__global__ void counts_kernel(const int* __restrict__ batch, int* __restrict__ counts, int n) {
    int i = blockIdx.x * blockDim.x + threadIdx.x;
    if (i < n) atomicAdd(&counts[batch[i]], 1);
}

__global__ void pool_kernel(const float* __restrict__ h, const int* __restrict__ batch,
                            float* __restrict__ gsum, int n) {
    int c = threadIdx.x;
    int r0 = blockIdx.x * 256;
    int r1 = min(r0 + 256, n);
    int cur = -1;
    float acc = 0.f;
    for (int r = r0; r < r1; ++r) {
        int g = batch[r];
        if (g != cur) {
            if (cur >= 0) atomicAdd(&gsum[(size_t)cur * 128 + c], acc);
            cur = g; acc = 0.f;
        }
        acc += h[(size_t)r * 128 + c];
    }
    if (cur >= 0) atomicAdd(&gsum[(size_t)cur * 128 + c], acc);
}

__global__ void mlp_kernel(const float* __restrict__ gsum, const int* __restrict__ counts,
                           const float* __restrict__ w1, const float* __restrict__ b1,
                           const float* __restrict__ w2, const float* __restrict__ b2,
                           const double* __restrict__ norm_slots, const double* __restrict__ cross_slots,
                           float* __restrict__ out) {
    __shared__ float gm[128];
    int g = blockIdx.x;
    int t = threadIdx.x;
    float cnt = fmaxf((float)counts[g], 1.f);
    gm[t]      = gsum[(size_t)g * 128 + t] / cnt;
    gm[t + 64] = gsum[(size_t)g * 128 + 64 + t] / cnt;
    __syncthreads();
    float z = b1[t];
    for (int k = 0; k < 128; ++k) z += gm[k] * w1[(size_t)k * 64 + t];
    z = fmaxf(z, 0.f);
    float p0 = z * w2[t * 2 + 0];
    float p1 = z * w2[t * 2 + 1];
    for (int off = 32; off > 0; off >>= 1) {
        p0 += __shfl_down(p0, off, 64);
        p1 += __shfl_down(p1, off, 64);
    }
    if (t == 0) {
        out[g * 2 + 0] = p0 + b2[0];
        out[g * 2 + 1] = p1 + b2[1];
    }
    if (g == 0) {
        double ns = 0.0, cs = 0.0;
        for (int i = t; i < 256; i += 64) { ns += norm_slots[i]; cs += cross_slots[i]; }
        for (int off = 32; off > 0; off >>= 1) {
            ns += __shfl_down(ns, off, 64);
            cs += __shfl_down(cs, off, 64);
        }
        if (t == 0) out[256] = (float)((ns - 2.0 * cs) / ((double)NEDGES * 4.0));
    }
}

// ------------------------------------------------------------------ launch
extern "C" void kernel_launch(void* const* d_in, const int* in_sizes, int n_in,
                              void* d_out, int out_size, void* d_ws, size_t ws_size,
                              hipStream_t stream) {
    const float* x      = (const float*)d_in[0];
    const float* w_in   = (const float*)d_in[1];
    const float* b_in   = (const float*)d_in[2];
    const float* ln_g   = (const float*)d_in[3];
    const float* ln_b   = (const float*)d_in[4];
    const float* cheb_w = (const float*)d_in[5];
    const float* cheb_b = (const float*)d_in[6];
    const float* bn_g   = (const float*)d_in[7];
    const float* bn_b   = (const float*)d_in[8];
    const float* w1     = (const float*)d_in[9];
    const float* b1     = (const float*)d_in[10];
    const float* w2     = (const float*)d_in[11];
    const float* b2     = (const float*)d_in[12];
    const int*   eidx   = (const int*)d_in[13];
    const int*   batch  = (const int*)d_in[14];
    const int* src = eidx;
    const int* dst = eidx + NEDGES;
    float* out = (float*)d_out;

    char* ws = (char*)d_ws;
    size_t off = 0;
    auto alloc = [&](size_t bytes) -> void* {
        void* p = ws + off;
        off = (off + bytes + 255) & ~(size_t)255;
        return p;
    };
    float* h    = (float*)alloc((size_t)NNODES * 128 * 4);
    float* t1   = (float*)alloc((size_t)NNODES * 128 * 4);
    float* sbuf = (float*)alloc((size_t)NNODES * 128 * 4);   // s = L*t1
    float* ob   = (float*)alloc((size_t)NNODES * 128 * 4);
    unsigned short* h16  = (unsigned short*)alloc((size_t)NNODES * 128 * 2);
    unsigned short* t116 = (unsigned short*)ob;              // alias: dead before gemm writes ob
    unsigned short* Wsp  = (unsigned short*)alloc((size_t)10 * 2048 * 16 * 2);
    int* outdeg   = (int*)alloc((size_t)NNODES * 4);
    int* indeg    = (int*)alloc((size_t)NNODES * 4);
    float* dinv   = (float*)alloc((size_t)NNODES * 4);
    int* row_off  = (int*)alloc((size_t)(NNODES + 1) * 4);
    int* cursor   = (int*)alloc((size_t)NNODES * 4);
    int* colv     = (int*)alloc((size_t)NEDGES * 4);
    float* colstats = (float*)alloc(256 * 4);
    float* ssbuf    = (float*)alloc(256 * 4);
    double* norm_slots  = (double*)alloc(256 * 8);
    double* cross_slots = (double*)alloc(256 * 8);
    float* gsum   = (float*)alloc((size_t)NGRAPH * 128 * 4);
    int* counts   = (int*)alloc((size_t)NGRAPH * 4);
    float* colsum = colstats, *colsumsq = colstats + 128;

    hipMemsetAsync(outdeg, 0, (size_t)NNODES * 4, stream);
    hipMemsetAsync(indeg, 0, (size_t)NNODES * 4, stream);
    hipMemsetAsync(norm_slots, 0, 256 * 8, stream);
    hipMemsetAsync(cross_slots, 0, 256 * 8, stream);
    hipMemsetAsync(gsum, 0, (size_t)NGRAPH * 128 * 4, stream);
    hipMemsetAsync(counts, 0, (size_t)NGRAPH * 4, stream);

    int tE = (NEDGES + 255) / 256;
    int tN = (NNODES + 255) / 256;
    deg_kernel<<<tE, 256, 0, stream>>>(src, dst, outdeg, indeg, NEDGES);
    dinv_kernel<<<tN, 256, 0, stream>>>(outdeg, dinv, NNODES);
    scan_kernel<<<1, 1024, 0, stream>>>(indeg, row_off, NNODES);
    cursor_copy_kernel<<<tN, 256, 0, stream>>>(row_off, cursor, NNODES);
    fill_kernel<<<tE, 256, 0, stream>>>(src, dst, cursor, colv, NEDGES);
    wprep_kernel<<<10, 256, 0, stream>>>(w_in, cheb_w, Wsp);

    int gemmBlocks = (NNODES + 63) / 64;
    int waveBlocks = (NNODES * 64 + 255) / 256;

    // embed: h0 = ReLU(LN(x @ w_in + b_in)), fp32 + bf16
    gemm_mfma<1, 0><<<gemmBlocks, 256, 0, stream>>>(x, nullptr, nullptr, Wsp, b_in, h, h16,
                                                    ln_g, ln_b, nullptr, nullptr, NNODES);

    for (int l = 0; l < 3; ++l) {
        hipMemsetAsync(colstats, 0, 256 * 4, stream);
        // t1 = L h  (gather h16) ; fused cross(h), norm(h) ; writes t1 fp32 + bf16
        spmm_kernel<0><<<waveBlocks, 256, 0, stream>>>(h16, h, t1, t116, row_off, colv, dinv,
                                                       outdeg, indeg, NNODES, norm_slots, cross_slots);
        // s = L t1 (gather t116)
        spmm_kernel<1><<<waveBlocks, 256, 0, stream>>>(t116, nullptr, sbuf, nullptr, row_off, colv, dinv,
                                                       outdeg, indeg, NNODES, nullptr, nullptr);
        // ob = h(W0-W2) + t1 W1 + s (2W2) + b ; BN col stats
        gemm_mfma<3, 1><<<gemmBlocks, 256, 0, stream>>>(h, t1, sbuf,
            Wsp + (size_t)(1 + 3 * l) * 2048 * 16, cheb_b + (size_t)l * 128, ob, nullptr,
            nullptr, nullptr, colsum, colsumsq, NNODES);
        bnscale_kernel<<<1, 128, 0, stream>>>(colsum, colsumsq, bn_g + (size_t)l * 128,
                                              bn_b + (size_t)l * 128, ssbuf, NNODES);
        int total4 = NNODES * 128 / 4;
        bnrelu_kernel<<<(total4 + 255) / 256, 256, 0, stream>>>(ob, ssbuf, h, h16, total4);
    }
    // final hidden's cross + norm
    spmm_kernel<2><<<waveBlocks, 256, 0, stream>>>(h16, h, nullptr, nullptr, row_off, colv, dinv,
                                                   outdeg, indeg, NNODES, norm_slots, cross_slots);

    counts_kernel<<<tN, 256, 0, stream>>>(batch, counts, NNODES);
    pool_kernel<<<(NNODES + 255) / 256, 128, 0, stream>>>(h, batch, gsum, NNODES);
    mlp_kernel<<<NGRAPH, 64, 0, stream>>>(gsum, counts, w1, b1, w2, b2,
                                          norm_slots, cross_slots, out);
}

// Round 4
// 940.714 us; speedup vs baseline: 6.4101x; 1.1860x over previous
//
#include <hip/hip_runtime.h>
#include <hip/hip_bf16.h>

#define NNODES 50000
#define NEDGES 800000
#define NGRAPH 128
#define EPSV 1e-5f

typedef __attribute__((ext_vector_type(8))) short bf16x8;
typedef __attribute__((ext_vector_type(4))) float f32x4;

__device__ __forceinline__ unsigned short f2bf(float f) {
    unsigned u = __float_as_uint(f);
    return (unsigned short)((u + 0x7fffu + ((u >> 16) & 1u)) >> 16);
}
__device__ __forceinline__ float bf2f(unsigned short h) {
    return __uint_as_float(((unsigned)h) << 16);
}

// ------------------------------------------------------------------ small prep
__global__ void deg_kernel(const int* __restrict__ src, const int* __restrict__ dst,
                           int* __restrict__ outdeg, int* __restrict__ indeg, int E) {
    int e = blockIdx.x * blockDim.x + threadIdx.x;
    if (e < E) {
        atomicAdd(&outdeg[src[e]], 1);
        atomicAdd(&indeg[dst[e]], 1);
    }
}

__global__ void dinv_kernel(const int* __restrict__ outdeg, float* __restrict__ dinv, int n) {
    int i = blockIdx.x * blockDim.x + threadIdx.x;
    if (i < n) {
        int d = outdeg[i];
        dinv[i] = (d > 0) ? rsqrtf((float)d) : 0.0f;
    }
}

// single-block exclusive scan; writes row_off AND cursor
__global__ void scan_kernel(const int* __restrict__ deg, int* __restrict__ row_off,
                            int* __restrict__ cursor, int n) {
    const int TPB = 1024;
    __shared__ int sh[TPB];
    int t = threadIdx.x;
    int per = (n + TPB - 1) / TPB;
    int s0 = t * per, s1 = min(s0 + per, n);
    int sum = 0;
    for (int i = s0; i < s1; ++i) sum += deg[i];
    sh[t] = sum;
    __syncthreads();
    for (int off = 1; off < TPB; off <<= 1) {
        int x = (t >= off) ? sh[t - off] : 0;
        __syncthreads();
        sh[t] += x;
        __syncthreads();
    }
    int run = sh[t] - sum;
    for (int i = s0; i < s1; ++i) { row_off[i] = run; cursor[i] = run; run += deg[i]; }
    if (t == TPB - 1) row_off[n] = sh[t];
}

__global__ void fill_kernel(const int* __restrict__ src, const int* __restrict__ dst,
                            int* __restrict__ cursor, int* __restrict__ col, int E) {
    int e = blockIdx.x * blockDim.x + threadIdx.x;
    if (e < E) {
        int d = dst[e];
        int pos = atomicAdd(&cursor[d], 1);
        col[pos] = src[e];
    }
}

// batch is sorted: start[g] = lower_bound(batch, g), g in [0, NGRAPH]
__global__ void bounds_kernel(const int* __restrict__ batch, int* __restrict__ start, int n) {
    int g = threadIdx.x;
    if (g <= NGRAPH) {
        int lo = 0, hi = n;
        while (lo < hi) {
            int mid = (lo + hi) >> 1;
            if (batch[mid] < g) lo = mid + 1; else hi = mid;
        }
        start[g] = lo;
    }
}

// ------------------------------------------------------------------ W prep: split fp32 -> bf16 hi/lo in MFMA lane order
// part 0 = w_in ; part 1+3l+k = cheb (recurrence folded: W0-W2, W1, 2*W2)
__global__ void wprep_kernel(const float* __restrict__ w_in, const float* __restrict__ cheb_w,
                             unsigned short* __restrict__ Wsp) {
    int p = blockIdx.x;            // 0..9
    int t = threadIdx.x;           // 256
    for (int s8 = 0; s8 < 8; ++s8) {
        int slot = s8 * 256 + t;   // 0..2047
        int kc = slot >> 9, ct = (slot >> 6) & 7, lane = slot & 63;
        int q = lane >> 4, nn = lane & 15;
        unsigned short* o = Wsp + ((size_t)p * 2048 + slot) * 16;
#pragma unroll
        for (int j = 0; j < 8; ++j) {
            int k = kc * 32 + q * 8 + j, c = ct * 16 + nn;
            float v;
            if (p == 0) {
                v = w_in[k * 128 + c];
            } else {
                int pl = (p - 1) / 3, kk = (p - 1) % 3;
                v = cheb_w[((size_t)(pl * 3 + kk) * 128 + k) * 128 + c];
                if (kk == 0) v -= cheb_w[((size_t)(pl * 3 + 2) * 128 + k) * 128 + c];
                else if (kk == 2) v *= 2.f;
            }
            unsigned short hi = f2bf(v);
            o[j] = hi;
            o[8 + j] = f2bf(v - bf2f(hi));
        }
    }
}

// ------------------------------------------------------------------ MFMA GEMM (LDS-free, split bf16)
template <int NPARTS, int EPI>
__global__ __launch_bounds__(256) void gemm_mfma(
    const float* __restrict__ A0, const float* __restrict__ A1, const float* __restrict__ A2,
    const unsigned short* __restrict__ Wsp, const float* __restrict__ bias,
    float* __restrict__ outp, unsigned short* __restrict__ out16,
    const float* __restrict__ g0, const float* __restrict__ b0,
    float* __restrict__ colsum, float* __restrict__ colsumsq, int n) {
    __shared__ float red[256];
    int t = threadIdx.x, w = t >> 6, l = t & 63;
    int m = l & 15, qk = l >> 4;
    int rowA = blockIdx.x * 64 + w * 16 + m;
    red[t] = 0.f;
    __syncthreads();

    f32x4 acc[8];
#pragma unroll
    for (int ct = 0; ct < 8; ++ct) acc[ct] = (f32x4){0.f, 0.f, 0.f, 0.f};

    const float* Ap[3] = {A0, A1, A2};
    bool valid = rowA < n;
#pragma unroll
    for (int p = 0; p < NPARTS; ++p) {
        const float* arow = Ap[p] + (size_t)rowA * 128;
#pragma unroll
        for (int kc = 0; kc < 4; ++kc) {
            float4 x0, x1;
            if (valid) {
                x0 = *(const float4*)&arow[kc * 32 + qk * 8];
                x1 = *(const float4*)&arow[kc * 32 + qk * 8 + 4];
            } else {
                x0 = make_float4(0.f, 0.f, 0.f, 0.f); x1 = x0;
            }
            float xs[8] = {x0.x, x0.y, x0.z, x0.w, x1.x, x1.y, x1.z, x1.w};
            bf16x8 ah, al;
#pragma unroll
            for (int j = 0; j < 8; ++j) {
                unsigned short hi = f2bf(xs[j]);
                ah[j] = (short)hi;
                al[j] = (short)f2bf(xs[j] - bf2f(hi));
            }
            const unsigned short* wb = Wsp + ((size_t)((p * 4 + kc) * 8) * 64 + l) * 16;
#pragma unroll
            for (int ct = 0; ct < 8; ++ct) {
                bf16x8 bh = *(const bf16x8*)(wb + (size_t)ct * 64 * 16);
                bf16x8 bl = *(const bf16x8*)(wb + (size_t)ct * 64 * 16 + 8);
                acc[ct] = __builtin_amdgcn_mfma_f32_16x16x32_bf16(ah, bh, acc[ct], 0, 0, 0);
                acc[ct] = __builtin_amdgcn_mfma_f32_16x16x32_bf16(al, bh, acc[ct], 0, 0, 0);
                acc[ct] = __builtin_amdgcn_mfma_f32_16x16x32_bf16(ah, bl, acc[ct], 0, 0, 0);
            }
        }
    }

    // C/D layout: col = ct*16 + m, row = blk*64 + w*16 + qk*4 + j
    int rowC0 = blockIdx.x * 64 + w * 16 + qk * 4;
    if (EPI == 0) {
        float rs[4] = {0.f, 0.f, 0.f, 0.f}, rss[4] = {0.f, 0.f, 0.f, 0.f};
#pragma unroll
        for (int ct = 0; ct < 8; ++ct) {
            float b = bias[ct * 16 + m];
#pragma unroll
            for (int j = 0; j < 4; ++j) {
                float v = acc[ct][j] + b;
                acc[ct][j] = v;
                rs[j] += v; rss[j] += v * v;
            }
        }
#pragma unroll
        for (int off = 1; off < 16; off <<= 1) {
#pragma unroll
            for (int j = 0; j < 4; ++j) {
                rs[j] += __shfl_xor(rs[j], off, 64);
                rss[j] += __shfl_xor(rss[j], off, 64);
            }
        }
        float mean[4], rstd[4];
#pragma unroll
        for (int j = 0; j < 4; ++j) {
            mean[j] = rs[j] * (1.f / 128.f);
            float var = rss[j] * (1.f / 128.f) - mean[j] * mean[j];
            rstd[j] = rsqrtf(var + EPSV);
        }
#pragma unroll
        for (int ct = 0; ct < 8; ++ct) {
            int c = ct * 16 + m;
            float gg = g0[c], bb = b0[c];
#pragma unroll
            for (int j = 0; j < 4; ++j) {
                int gr = rowC0 + j;
                if (gr < n) {
                    float x = (acc[ct][j] - mean[j]) * rstd[j] * gg + bb;
                    x = fmaxf(x, 0.f);
                    outp[(size_t)gr * 128 + c] = x;
                    out16[(size_t)gr * 128 + c] = f2bf(x);
                }
            }
        }
    } else {
#pragma unroll
        for (int ct = 0; ct < 8; ++ct) {
            int c = ct * 16 + m;
            float b = bias[c];
            float s = 0.f, ss = 0.f;
#pragma unroll
            for (int j = 0; j < 4; ++j) {
                int gr = rowC0 + j;
                if (gr < n) {
                    float v = acc[ct][j] + b;
                    outp[(size_t)gr * 128 + c] = v;
                    s += v; ss += v * v;
                }
            }
            s += __shfl_xor(s, 16, 64);  ss += __shfl_xor(ss, 16, 64);
            s += __shfl_xor(s, 32, 64);  ss += __shfl_xor(ss, 32, 64);
            if (qk == 0) {
                atomicAdd(&red[c], s);
                atomicAdd(&red[128 + c], ss);
            }
        }
        __syncthreads();
        if (t < 128) {
            atomicAdd(&colsum[t], red[t]);
            atomicAdd(&colsumsq[t], red[128 + t]);
        }
    }
}

// ------------------------------------------------------------------ spmm (wave per node, bf16 gathers, 16 rows in flight)
// MODE 0: spmm + bf16 out + stats ; MODE 1: spmm only ; MODE 2: stats only
template <int MODE>
__global__ void spmm_kernel(const unsigned short* __restrict__ g16,
                            const float* __restrict__ self32,
                            float* __restrict__ dstv, unsigned short* __restrict__ dst16,
                            const int* __restrict__ row_off, const int* __restrict__ col,
                            const float* __restrict__ dinv,
                            const int* __restrict__ outdeg, const int* __restrict__ indeg,
                            int n, double* __restrict__ norm_slots, double* __restrict__ cross_slots) {
    int w = (int)((blockIdx.x * (unsigned)blockDim.x + threadIdx.x) >> 6);
    if (w >= n) return;
    int lane = threadIdx.x & 63;
    int g = lane >> 5;          // neighbor slot group (0/1)
    int q = lane & 31;          // ushort4 column index (covers 128 cols)
    int s = row_off[w], e = row_off[w + 1];
    float4 hi = make_float4(0.f, 0.f, 0.f, 0.f);
    if (MODE != 1) hi = *(const float4*)&self32[(size_t)w * 128 + q * 4];
    float4 acc = make_float4(0.f, 0.f, 0.f, 0.f);
    float cr = 0.f;
    for (int base = s; base < e; base += 64) {
        int mm = min(e - base, 64);
        int idx = 0; float dv = 0.f;
        if (lane < mm) { idx = col[base + lane]; dv = dinv[idx]; }
        int iters = (mm + 15) >> 4;          // 16 neighbors/iter (8 per group)
        for (int it = 0; it < iters; ++it) {
            int sb = (it << 4) + (g << 3);   // this group's first slot
            int jj[8]; float dd[8];
#pragma unroll
            for (int u = 0; u < 8; ++u) {
                jj[u] = __shfl(idx, sb + u, 64);
                dd[u] = __shfl(dv, sb + u, 64);
            }
            ushort4 uu[8];
#pragma unroll
            for (int u = 0; u < 8; ++u) {
                uu[u] = make_ushort4(0, 0, 0, 0);
                if (sb + u < mm) uu[u] = *(const ushort4*)&g16[(size_t)jj[u] * 128 + q * 4];
            }
#pragma unroll
            for (int u = 0; u < 8; ++u) {
                float4 v = make_float4(bf2f(uu[u].x), bf2f(uu[u].y), bf2f(uu[u].z), bf2f(uu[u].w));
                if (MODE != 2) {
                    acc.x += dd[u] * v.x; acc.y += dd[u] * v.y;
                    acc.z += dd[u] * v.z; acc.w += dd[u] * v.w;
                }
                if (MODE != 1)
                    cr += hi.x * v.x + hi.y * v.y + hi.z * v.z + hi.w * v.w;
            }
        }
    }
    if (MODE != 2) {
        acc.x += __shfl_xor(acc.x, 32, 64);
        acc.y += __shfl_xor(acc.y, 32, 64);
        acc.z += __shfl_xor(acc.z, 32, 64);
        acc.w += __shfl_xor(acc.w, 32, 64);
        if (g == 0) {
            float di = dinv[w];
            float4 r = make_float4(-di * acc.x, -di * acc.y, -di * acc.z, -di * acc.w);
            *(float4*)&dstv[(size_t)w * 128 + q * 4] = r;
            if (MODE == 0) {
                ushort4 u = make_ushort4(f2bf(r.x), f2bf(r.y), f2bf(r.z), f2bf(r.w));
                *(ushort4*)&dst16[(size_t)w * 128 + q * 4] = u;
            }
        }
    }
    if (MODE != 1) {
        float nt = 0.5f * (hi.x*hi.x + hi.y*hi.y + hi.z*hi.z + hi.w*hi.w);
        for (int off = 32; off > 0; off >>= 1) {
            cr += __shfl_down(cr, off, 64);
            nt += __shfl_down(nt, off, 64);
        }
        if (lane == 0) {
            int slot = w & 255;
            atomicAdd(&cross_slots[slot], (double)cr);
            atomicAdd(&norm_slots[slot], (double)nt * (double)(outdeg[w] + indeg[w]));
        }
    }
}

// ------------------------------------------------------------------ BN apply
__global__ void bnscale_kernel(const float* __restrict__ colsum, const float* __restrict__ colsumsq,
                               const float* __restrict__ bn_g, const float* __restrict__ bn_b,
                               float* __restrict__ ss, int n) {
    int c = threadIdx.x;
    if (c < 128) {
        float m = colsum[c] / (float)n;
        float v = colsumsq[c] / (float)n - m * m;
        float sc = bn_g[c] * rsqrtf(v + EPSV);
        ss[c] = sc;
        ss[128 + c] = bn_b[c] - m * sc;
    }
}

__global__ void bnrelu_kernel(const float* __restrict__ outv, const float* __restrict__ ss,
                              float* __restrict__ h, unsigned short* __restrict__ h16, int total4) {
    int i = blockIdx.x * blockDim.x + threadIdx.x;
    if (i >= total4) return;
    float4 o = ((const float4*)outv)[i];
    int c = (i * 4) & 127;
    float4 sc = *(const float4*)&ss[c];
    float4 sh = *(const float4*)&ss[128 + c];
    float4 r;
    r.x = fmaxf(o.x * sc.x + sh.x, 0.f);
    r.y = fmaxf(o.y * sc.y + sh.y, 0.f);
    r.z = fmaxf(o.z * sc.z + sh.z, 0.f);
    r.w = fmaxf(o.w * sc.w + sh.w, 0.f);
    ((float4*)h)[i] = r;
    ushort4 u = make_ushort4(f2bf(r.x), f2bf(r.y), f2bf(r.z), f2bf(r.w));
    ((ushort4*)h16)[i] = u;
}

// ------------------------------------------------------------------ fused pool + MLP (block per graph, atomic-free)
__global__ void poolmlp_kernel(const float* __restrict__ h, const int* __restrict__ start,
                               const float* __restrict__ w1, const float* __restrict__ b1,
                               const float* __restrict__ w2, const float* __restrict__ b2,
                               const double* __restrict__ norm_slots,
                               const double* __restrict__ cross_slots,
                               float* __restrict__ out) {
    __shared__ float sm[2][128];
    __shared__ float gm[128];
    int g = blockIdx.x, t = threadIdx.x;   // 256 threads
    int half = t >> 7, c = t & 127;
    int s = start[g], e = start[g + 1];
    float acc = 0.f;
    for (int r = s + half; r < e; r += 2) acc += h[(size_t)r * 128 + c];
    sm[half][c] = acc;
    __syncthreads();
    if (t < 128) {
        float cnt = fmaxf((float)(e - s), 1.f);
        gm[t] = (sm[0][t] + sm[1][t]) / cnt;
    }
    __syncthreads();
    if (t < 64) {
        float z = b1[t];
        for (int k = 0; k < 128; ++k) z += gm[k] * w1[(size_t)k * 64 + t];
        z = fmaxf(z, 0.f);
        float p0 = z * w2[t * 2 + 0];
        float p1 = z * w2[t * 2 + 1];
        for (int off = 32; off > 0; off >>= 1) {
            p0 += __shfl_down(p0, off, 64);
            p1 += __shfl_down(p1, off, 64);
        }
        if (t == 0) {
            out[g * 2 + 0] = p0 + b2[0];
            out[g * 2 + 1] = p1 + b2[1];
        }
    } else if (g == 0 && t < 128) {
        int l = t - 64;
        double ns = 0.0, cs = 0.0;
        for (int i = l; i < 256; i += 64) { ns += norm_slots[i]; cs += cross_slots[i]; }
        for (int off = 32; off > 0; off >>= 1) {
            ns += __shfl_down(ns, off, 64);
            cs += __shfl_down(cs, off, 64);
        }
        if (l == 0) out[256] = (float)((ns - 2.0 * cs) / ((double)NEDGES * 4.0));
    }
}

// ------------------------------------------------------------------ launch
extern "C" void kernel_launch(void* const* d_in, const int* in_sizes, int n_in,
                              void* d_out, int out_size, void* d_ws, size_t ws_size,
                              hipStream_t stream) {
    const float* x      = (const float*)d_in[0];
    const float* w_in   = (const float*)d_in[1];
    const float* b_in   = (const float*)d_in[2];
    const float* ln_g   = (const float*)d_in[3];
    const float* ln_b   = (const float*)d_in[4];
    const float* cheb_w = (const float*)d_in[5];
    const float* cheb_b = (const float*)d_in[6];
    const float* bn_g   = (const float*)d_in[7];
    const float* bn_b   = (const float*)d_in[8];
    const float* w1     = (const float*)d_in[9];
    const float* b1     = (const float*)d_in[10];
    const float* w2     = (const float*)d_in[11];
    const float* b2     = (const float*)d_in[12];
    const int*   eidx   = (const int*)d_in[13];
    const int*   batch  = (const int*)d_in[14];
    const int* src = eidx;
    const int* dst = eidx + NEDGES;
    float* out = (float*)d_out;

    char* ws = (char*)d_ws;
    size_t off = 0;
    auto alloc = [&](size_t bytes) -> void* {
        void* p = ws + off;
        off = (off + bytes + 255) & ~(size_t)255;
        return p;
    };
    float* h    = (float*)alloc((size_t)NNODES * 128 * 4);
    float* t1   = (float*)alloc((size_t)NNODES * 128 * 4);
    float* sbuf = (float*)alloc((size_t)NNODES * 128 * 4);   // s = L*t1
    float* ob   = (float*)alloc((size_t)NNODES * 128 * 4);
    unsigned short* h16  = (unsigned short*)alloc((size_t)NNODES * 128 * 2);
    unsigned short* t116 = (unsigned short*)ob;              // alias: dead before gemm writes ob
    unsigned short* Wsp  = (unsigned short*)alloc((size_t)10 * 2048 * 16 * 2);
    int* outdeg   = (int*)alloc((size_t)NNODES * 4);
    int* indeg    = (int*)alloc((size_t)NNODES * 4);
    float* dinv   = (float*)alloc((size_t)NNODES * 4);
    int* row_off  = (int*)alloc((size_t)(NNODES + 1) * 4);
    int* cursor   = (int*)alloc((size_t)NNODES * 4);
    int* colv     = (int*)alloc((size_t)NEDGES * 4);
    int* gstart   = (int*)alloc((size_t)(NGRAPH + 1) * 4);
    float* colstats = (float*)alloc(256 * 4);
    float* ssbuf    = (float*)alloc(256 * 4);
    double* norm_slots  = (double*)alloc(256 * 8);
    double* cross_slots = (double*)alloc(256 * 8);
    float* colsum = colstats, *colsumsq = colstats + 128;

    hipMemsetAsync(outdeg, 0, (size_t)NNODES * 4, stream);
    hipMemsetAsync(indeg, 0, (size_t)NNODES * 4, stream);
    hipMemsetAsync(norm_slots, 0, 256 * 8, stream);
    hipMemsetAsync(cross_slots, 0, 256 * 8, stream);

    int tE = (NEDGES + 255) / 256;
    int tN = (NNODES + 255) / 256;
    deg_kernel<<<tE, 256, 0, stream>>>(src, dst, outdeg, indeg, NEDGES);
    dinv_kernel<<<tN, 256, 0, stream>>>(outdeg, dinv, NNODES);
    scan_kernel<<<1, 1024, 0, stream>>>(indeg, row_off, cursor, NNODES);
    fill_kernel<<<tE, 256, 0, stream>>>(src, dst, cursor, colv, NEDGES);
    bounds_kernel<<<1, 256, 0, stream>>>(batch, gstart, NNODES);
    wprep_kernel<<<10, 256, 0, stream>>>(w_in, cheb_w, Wsp);

    int gemmBlocks = (NNODES + 63) / 64;
    int waveBlocks = (NNODES * 64 + 255) / 256;

    // embed: h0 = ReLU(LN(x @ w_in + b_in)), fp32 + bf16
    gemm_mfma<1, 0><<<gemmBlocks, 256, 0, stream>>>(x, nullptr, nullptr, Wsp, b_in, h, h16,
                                                    ln_g, ln_b, nullptr, nullptr, NNODES);

    for (int l = 0; l < 3; ++l) {
        hipMemsetAsync(colstats, 0, 256 * 4, stream);
        // t1 = L h  (gather h16) ; fused cross(h), norm(h)
        spmm_kernel<0><<<waveBlocks, 256, 0, stream>>>(h16, h, t1, t116, row_off, colv, dinv,
                                                       outdeg, indeg, NNODES, norm_slots, cross_slots);
        // s = L t1 (gather t116)
        spmm_kernel<1><<<waveBlocks, 256, 0, stream>>>(t116, nullptr, sbuf, nullptr, row_off, colv, dinv,
                                                       outdeg, indeg, NNODES, nullptr, nullptr);
        // ob = h(W0-W2) + t1 W1 + s (2W2) + b ; BN col stats
        gemm_mfma<3, 1><<<gemmBlocks, 256, 0, stream>>>(h, t1, sbuf,
            Wsp + (size_t)(1 + 3 * l) * 2048 * 16, cheb_b + (size_t)l * 128, ob, nullptr,
            nullptr, nullptr, colsum, colsumsq, NNODES);
        bnscale_kernel<<<1, 128, 0, stream>>>(colsum, colsumsq, bn_g + (size_t)l * 128,
                                              bn_b + (size_t)l * 128, ssbuf, NNODES);
        int total4 = NNODES * 128 / 4;
        bnrelu_kernel<<<(total4 + 255) / 256, 256, 0, stream>>>(ob, ssbuf, h, h16, total4);
    }
    // final hidden's cross + norm
    spmm_kernel<2><<<waveBlocks, 256, 0, stream>>>(h16, h, nullptr, nullptr, row_off, colv, dinv,
                                                   outdeg, indeg, NNODES, norm_slots, cross_slots);

    poolmlp_kernel<<<NGRAPH, 256, 0, stream>>>(h, gstart, w1, b1, w2, b2,
                                               norm_slots, cross_slots, out);
}

// Round 5
// 881.614 us; speedup vs baseline: 6.8398x; 1.0670x over previous
//
#include <hip/hip_runtime.h>
#include <hip/hip_bf16.h>

#define NNODES 50000
#define NEDGES 800000
#define NGRAPH 128
#define EPSV 1e-5f

typedef __attribute__((ext_vector_type(8))) short bf16x8;
typedef __attribute__((ext_vector_type(8))) unsigned short us16x8;
typedef __attribute__((ext_vector_type(4))) float f32x4;

__device__ __forceinline__ unsigned short f2bf(float f) {
    unsigned u = __float_as_uint(f);
    return (unsigned short)((u + 0x7fffu + ((u >> 16) & 1u)) >> 16);
}
__device__ __forceinline__ float bf2f(unsigned short h) {
    return __uint_as_float(((unsigned)h) << 16);
}

// ------------------------------------------------------------------ small prep
__global__ void deg_kernel(const int* __restrict__ src, const int* __restrict__ dst,
                           int* __restrict__ outdeg, int* __restrict__ indeg, int E) {
    int e = blockIdx.x * blockDim.x + threadIdx.x;
    if (e < E) {
        atomicAdd(&outdeg[src[e]], 1);
        atomicAdd(&indeg[dst[e]], 1);
    }
}

__global__ void dinv_kernel(const int* __restrict__ outdeg, float* __restrict__ dinv, int n) {
    int i = blockIdx.x * blockDim.x + threadIdx.x;
    if (i < n) {
        int d = outdeg[i];
        dinv[i] = (d > 0) ? rsqrtf((float)d) : 0.0f;
    }
}

// ---- hierarchical exclusive scan (coalesced, parallel) ----
__global__ void scan_part(const int* __restrict__ deg, int* __restrict__ bsum, int n) {
    __shared__ int sh[256];
    int t = threadIdx.x, i = blockIdx.x * 256 + t;
    sh[t] = (i < n) ? deg[i] : 0;
    __syncthreads();
    for (int off = 128; off > 0; off >>= 1) {
        if (t < off) sh[t] += sh[t + off];
        __syncthreads();
    }
    if (t == 0) bsum[blockIdx.x] = sh[0];
}

__global__ void scan_top(int* __restrict__ bsum, int* __restrict__ total, int nb) {
    __shared__ int sh[256];
    int t = threadIdx.x;
    int v = (t < nb) ? bsum[t] : 0;
    sh[t] = v;
    __syncthreads();
    for (int off = 1; off < 256; off <<= 1) {
        int x = (t >= off) ? sh[t - off] : 0;
        __syncthreads();
        sh[t] += x;
        __syncthreads();
    }
    if (t < nb) bsum[t] = sh[t] - v;          // exclusive block offsets
    if (t == nb - 1) total[0] = sh[t];
}

__global__ void scan_apply(const int* __restrict__ deg, const int* __restrict__ bsum,
                           int* __restrict__ row_off, int* __restrict__ cursor, int n) {
    __shared__ int sh[256];
    int t = threadIdx.x, i = blockIdx.x * 256 + t;
    int v = (i < n) ? deg[i] : 0;
    sh[t] = v;
    __syncthreads();
    for (int off = 1; off < 256; off <<= 1) {
        int x = (t >= off) ? sh[t - off] : 0;
        __syncthreads();
        sh[t] += x;
        __syncthreads();
    }
    if (i < n) {
        int r = bsum[blockIdx.x] + sh[t] - v;
        row_off[i] = r;
        cursor[i] = r;
    }
}

__global__ void fill_kernel(const int* __restrict__ src, const int* __restrict__ dst,
                            int* __restrict__ cursor, int* __restrict__ col, int E) {
    int e = blockIdx.x * blockDim.x + threadIdx.x;
    if (e < E) {
        int d = dst[e];
        int pos = atomicAdd(&cursor[d], 1);
        col[pos] = src[e];
    }
}

// batch is sorted: start[g] = lower_bound(batch, g)
__global__ void bounds_kernel(const int* __restrict__ batch, int* __restrict__ start, int n) {
    int g = threadIdx.x;
    if (g <= NGRAPH) {
        int lo = 0, hi = n;
        while (lo < hi) {
            int mid = (lo + hi) >> 1;
            if (batch[mid] < g) lo = mid + 1; else hi = mid;
        }
        start[g] = lo;
    }
}

// ------------------------------------------------------------------ W prep: split fp32 -> bf16 hi/lo in MFMA lane order
// part 0 = w_in ; part 1+3l+k = cheb (recurrence folded: W0-W2, W1, 2*W2)
__global__ void wprep_kernel(const float* __restrict__ w_in, const float* __restrict__ cheb_w,
                             unsigned short* __restrict__ Wsp) {
    int p = blockIdx.x;            // 0..9
    int t = threadIdx.x;           // 256
    for (int s8 = 0; s8 < 8; ++s8) {
        int slot = s8 * 256 + t;   // 0..2047
        int kc = slot >> 9, ct = (slot >> 6) & 7, lane = slot & 63;
        int q = lane >> 4, nn = lane & 15;
        unsigned short* o = Wsp + ((size_t)p * 2048 + slot) * 16;
#pragma unroll
        for (int j = 0; j < 8; ++j) {
            int k = kc * 32 + q * 8 + j, c = ct * 16 + nn;
            float v;
            if (p == 0) {
                v = w_in[k * 128 + c];
            } else {
                int pl = (p - 1) / 3, kk = (p - 1) % 3;
                v = cheb_w[((size_t)(pl * 3 + kk) * 128 + k) * 128 + c];
                if (kk == 0) v -= cheb_w[((size_t)(pl * 3 + 2) * 128 + k) * 128 + c];
                else if (kk == 2) v *= 2.f;
            }
            unsigned short hi = f2bf(v);
            o[j] = hi;
            o[8 + j] = f2bf(v - bf2f(hi));
        }
    }
}

// ------------------------------------------------------------------ MFMA GEMM (LDS-free)
// AF32=1: A fp32, split hi/lo (3 MFMAs) ; AF32=0: A bf16 (2 MFMAs)
template <int NPARTS, int EPI, int AF32>
__global__ __launch_bounds__(256) void gemm_mfma(
    const void* __restrict__ A0v, const void* __restrict__ A1v, const void* __restrict__ A2v,
    const unsigned short* __restrict__ Wsp, const float* __restrict__ bias,
    float* __restrict__ outp, unsigned short* __restrict__ out16,
    const float* __restrict__ g0, const float* __restrict__ b0,
    float* __restrict__ colsum, float* __restrict__ colsumsq, int n) {
    __shared__ float red[256];
    int t = threadIdx.x, w = t >> 6, l = t & 63;
    int m = l & 15, qk = l >> 4;
    int rowA = blockIdx.x * 64 + w * 16 + m;
    red[t] = 0.f;
    __syncthreads();

    f32x4 acc[8];
#pragma unroll
    for (int ct = 0; ct < 8; ++ct) acc[ct] = (f32x4){0.f, 0.f, 0.f, 0.f};

    bool valid = rowA < n;
#pragma unroll
    for (int p = 0; p < NPARTS; ++p) {
#pragma unroll
        for (int kc = 0; kc < 4; ++kc) {
            bf16x8 ah, al;
            if (AF32) {
                const float* arow = (const float*)A0v;
                if (p == 1) arow = (const float*)A1v;
                if (p == 2) arow = (const float*)A2v;
                arow += (size_t)rowA * 128;
                float4 x0, x1;
                if (valid) {
                    x0 = *(const float4*)&arow[kc * 32 + qk * 8];
                    x1 = *(const float4*)&arow[kc * 32 + qk * 8 + 4];
                } else {
                    x0 = make_float4(0.f, 0.f, 0.f, 0.f); x1 = x0;
                }
                float xs[8] = {x0.x, x0.y, x0.z, x0.w, x1.x, x1.y, x1.z, x1.w};
#pragma unroll
                for (int j = 0; j < 8; ++j) {
                    unsigned short hi = f2bf(xs[j]);
                    ah[j] = (short)hi;
                    al[j] = (short)f2bf(xs[j] - bf2f(hi));
                }
            } else {
                const unsigned short* arow = (const unsigned short*)A0v;
                if (p == 1) arow = (const unsigned short*)A1v;
                if (p == 2) arow = (const unsigned short*)A2v;
                arow += (size_t)rowA * 128;
                if (valid) ah = *(const bf16x8*)&arow[kc * 32 + qk * 8];
                else ah = (bf16x8){0, 0, 0, 0, 0, 0, 0, 0};
            }
            const unsigned short* wb = Wsp + ((size_t)((p * 4 + kc) * 8) * 64 + l) * 16;
#pragma unroll
            for (int ct = 0; ct < 8; ++ct) {
                bf16x8 bh = *(const bf16x8*)(wb + (size_t)ct * 64 * 16);
                bf16x8 bl = *(const bf16x8*)(wb + (size_t)ct * 64 * 16 + 8);
                acc[ct] = __builtin_amdgcn_mfma_f32_16x16x32_bf16(ah, bh, acc[ct], 0, 0, 0);
                if (AF32)
                    acc[ct] = __builtin_amdgcn_mfma_f32_16x16x32_bf16(al, bh, acc[ct], 0, 0, 0);
                acc[ct] = __builtin_amdgcn_mfma_f32_16x16x32_bf16(ah, bl, acc[ct], 0, 0, 0);
            }
        }
    }

    // C/D layout: col = ct*16 + m, row = blk*64 + w*16 + qk*4 + j
    int rowC0 = blockIdx.x * 64 + w * 16 + qk * 4;
    if (EPI == 0) {
        float rs[4] = {0.f, 0.f, 0.f, 0.f}, rss[4] = {0.f, 0.f, 0.f, 0.f};
#pragma unroll
        for (int ct = 0; ct < 8; ++ct) {
            float b = bias[ct * 16 + m];
#pragma unroll
            for (int j = 0; j < 4; ++j) {
                float v = acc[ct][j] + b;
                acc[ct][j] = v;
                rs[j] += v; rss[j] += v * v;
            }
        }
#pragma unroll
        for (int off = 1; off < 16; off <<= 1) {
#pragma unroll
            for (int j = 0; j < 4; ++j) {
                rs[j] += __shfl_xor(rs[j], off, 64);
                rss[j] += __shfl_xor(rss[j], off, 64);
            }
        }
        float mean[4], rstd[4];
#pragma unroll
        for (int j = 0; j < 4; ++j) {
            mean[j] = rs[j] * (1.f / 128.f);
            float var = rss[j] * (1.f / 128.f) - mean[j] * mean[j];
            rstd[j] = rsqrtf(var + EPSV);
        }
#pragma unroll
        for (int ct = 0; ct < 8; ++ct) {
            int c = ct * 16 + m;
            float gg = g0[c], bb = b0[c];
#pragma unroll
            for (int j = 0; j < 4; ++j) {
                int gr = rowC0 + j;
                if (gr < n) {
                    float x = (acc[ct][j] - mean[j]) * rstd[j] * gg + bb;
                    x = fmaxf(x, 0.f);
                    outp[(size_t)gr * 128 + c] = x;
                    out16[(size_t)gr * 128 + c] = f2bf(x);
                }
            }
        }
    } else {
#pragma unroll
        for (int ct = 0; ct < 8; ++ct) {
            int c = ct * 16 + m;
            float b = bias[c];
            float s = 0.f, ss = 0.f;
#pragma unroll
            for (int j = 0; j < 4; ++j) {
                int gr = rowC0 + j;
                if (gr < n) {
                    float v = acc[ct][j] + b;
                    outp[(size_t)gr * 128 + c] = v;
                    s += v; ss += v * v;
                }
            }
            s += __shfl_xor(s, 16, 64);  ss += __shfl_xor(ss, 16, 64);
            s += __shfl_xor(s, 32, 64);  ss += __shfl_xor(ss, 32, 64);
            if (qk == 0) {
                atomicAdd(&red[c], s);
                atomicAdd(&red[128 + c], ss);
            }
        }
        __syncthreads();
        if (t < 128) {
            atomicAdd(&colsum[t], red[t]);
            atomicAdd(&colsumsq[t], red[128 + t]);
        }
    }
}

// ------------------------------------------------------------------ spmm (wave per node, 16-lane rows, bf16 in/out)
// MODE 0: dst16 = bf16(-dinv_i * sum_j dinv_j v_j) + stats ; MODE 1: dst16 only ; MODE 2: stats only
template <int MODE>
__global__ void spmm_kernel(const unsigned short* __restrict__ g16,
                            const float* __restrict__ self32,
                            unsigned short* __restrict__ dst16,
                            const int* __restrict__ row_off, const int* __restrict__ col,
                            const float* __restrict__ dinv,
                            const int* __restrict__ outdeg, const int* __restrict__ indeg,
                            int n, double* __restrict__ norm_slots, double* __restrict__ cross_slots) {
    int w = (int)((blockIdx.x * (unsigned)blockDim.x + threadIdx.x) >> 6);
    if (w >= n) return;
    int lane = threadIdx.x & 63;
    int g = lane >> 4;          // neighbor group (0..3)
    int q = lane & 15;          // 16B column chunk (8 bf16 each -> 128 cols)
    int s = row_off[w], e = row_off[w + 1];
    float hi[8];
    if (MODE != 1) {
        float4 a = *(const float4*)&self32[(size_t)w * 128 + q * 8];
        float4 b = *(const float4*)&self32[(size_t)w * 128 + q * 8 + 4];
        hi[0] = a.x; hi[1] = a.y; hi[2] = a.z; hi[3] = a.w;
        hi[4] = b.x; hi[5] = b.y; hi[6] = b.z; hi[7] = b.w;
    }
    float acc[8];
#pragma unroll
    for (int j = 0; j < 8; ++j) acc[j] = 0.f;
    float cr = 0.f;
    for (int base = s; base < e; base += 64) {
        int mm = min(e - base, 64);
        int idx = 0; float dv = 0.f;
        if (lane < mm) { idx = col[base + lane]; dv = dinv[idx]; }
        int iters = (mm + 31) >> 5;          // 32 neighbors/iter (8 per group)
        for (int it = 0; it < iters; ++it) {
            int sb = (it << 5) + (g << 3);   // this group's first slot
            int jj[8]; float dd[8];
#pragma unroll
            for (int u = 0; u < 8; ++u) {
                jj[u] = __shfl(idx, sb + u, 64);
                dd[u] = __shfl(dv, sb + u, 64);
            }
            us16x8 uu[8];
#pragma unroll
            for (int u = 0; u < 8; ++u) {
                uu[u] = (us16x8){0, 0, 0, 0, 0, 0, 0, 0};
                if (sb + u < mm) uu[u] = *(const us16x8*)&g16[(size_t)jj[u] * 128 + q * 8];
            }
#pragma unroll
            for (int u = 0; u < 8; ++u) {
#pragma unroll
                for (int j = 0; j < 8; ++j) {
                    float v = bf2f(uu[u][j]);
                    if (MODE != 2) acc[j] += dd[u] * v;
                    if (MODE != 1) cr += hi[j] * v;
                }
            }
        }
    }
    if (MODE != 2) {
        // combine the 4 neighbor groups (same q columns)
#pragma unroll
        for (int j = 0; j < 8; ++j) {
            acc[j] += __shfl_xor(acc[j], 16, 64);
            acc[j] += __shfl_xor(acc[j], 32, 64);
        }
        if (g == 0) {
            float di = dinv[w];
            us16x8 o;
#pragma unroll
            for (int j = 0; j < 8; ++j) o[j] = f2bf(-di * acc[j]);
            *(us16x8*)&dst16[(size_t)w * 128 + q * 8] = o;
        }
    }
    if (MODE != 1) {
        float nt = 0.f;
#pragma unroll
        for (int j = 0; j < 8; ++j) nt += hi[j] * hi[j];
        nt *= 0.25f;   // 4 groups replicate each column
        for (int off = 32; off > 0; off >>= 1) {
            cr += __shfl_down(cr, off, 64);
            nt += __shfl_down(nt, off, 64);
        }
        if (lane == 0) {
            int slot = w & 255;
            atomicAdd(&cross_slots[slot], (double)cr);
            atomicAdd(&norm_slots[slot], (double)nt * (double)(outdeg[w] + indeg[w]));
        }
    }
}

// ------------------------------------------------------------------ BN apply
__global__ void bnscale_kernel(const float* __restrict__ colsum, const float* __restrict__ colsumsq,
                               const float* __restrict__ bn_g, const float* __restrict__ bn_b,
                               float* __restrict__ ss, int n) {
    int c = threadIdx.x;
    if (c < 128) {
        float m = colsum[c] / (float)n;
        float v = colsumsq[c] / (float)n - m * m;
        float sc = bn_g[c] * rsqrtf(v + EPSV);
        ss[c] = sc;
        ss[128 + c] = bn_b[c] - m * sc;
    }
}

__global__ void bnrelu_kernel(const float* __restrict__ outv, const float* __restrict__ ss,
                              float* __restrict__ h, unsigned short* __restrict__ h16, int total4) {
    int i = blockIdx.x * blockDim.x + threadIdx.x;
    if (i >= total4) return;
    float4 o = ((const float4*)outv)[i];
    int c = (i * 4) & 127;
    float4 sc = *(const float4*)&ss[c];
    float4 sh = *(const float4*)&ss[128 + c];
    float4 r;
    r.x = fmaxf(o.x * sc.x + sh.x, 0.f);
    r.y = fmaxf(o.y * sc.y + sh.y, 0.f);
    r.z = fmaxf(o.z * sc.z + sh.z, 0.f);
    r.w = fmaxf(o.w * sc.w + sh.w, 0.f);
    ((float4*)h)[i] = r;
    ushort4 u = make_ushort4(f2bf(r.x), f2bf(r.y), f2bf(r.z), f2bf(r.w));
    ((ushort4*)h16)[i] = u;
}

// ------------------------------------------------------------------ fused pool + MLP (block per graph, atomic-free)
__global__ void poolmlp_kernel(const float* __restrict__ h, const int* __restrict__ start,
                               const float* __restrict__ w1, const float* __restrict__ b1,
                               const float* __restrict__ w2, const float* __restrict__ b2,
                               const double* __restrict__ norm_slots,
                               const double* __restrict__ cross_slots,
                               float* __restrict__ out) {
    __shared__ float sm[2][128];
    __shared__ float gm[128];
    int g = blockIdx.x, t = threadIdx.x;   // 256 threads
    int half = t >> 7, c = t & 127;
    int s = start[g], e = start[g + 1];
    float acc = 0.f;
    for (int r = s + half; r < e; r += 2) acc += h[(size_t)r * 128 + c];
    sm[half][c] = acc;
    __syncthreads();
    if (t < 128) {
        float cnt = fmaxf((float)(e - s), 1.f);
        gm[t] = (sm[0][t] + sm[1][t]) / cnt;
    }
    __syncthreads();
    if (t < 64) {
        float z = b1[t];
        for (int k = 0; k < 128; ++k) z += gm[k] * w1[(size_t)k * 64 + t];
        z = fmaxf(z, 0.f);
        float p0 = z * w2[t * 2 + 0];
        float p1 = z * w2[t * 2 + 1];
        for (int off = 32; off > 0; off >>= 1) {
            p0 += __shfl_down(p0, off, 64);
            p1 += __shfl_down(p1, off, 64);
        }
        if (t == 0) {
            out[g * 2 + 0] = p0 + b2[0];
            out[g * 2 + 1] = p1 + b2[1];
        }
    } else if (g == 0 && t < 128) {
        int l = t - 64;
        double ns = 0.0, cs = 0.0;
        for (int i = l; i < 256; i += 64) { ns += norm_slots[i]; cs += cross_slots[i]; }
        for (int off = 32; off > 0; off >>= 1) {
            ns += __shfl_down(ns, off, 64);
            cs += __shfl_down(cs, off, 64);
        }
        if (l == 0) out[256] = (float)((ns - 2.0 * cs) / ((double)NEDGES * 4.0));
    }
}

// ------------------------------------------------------------------ launch
extern "C" void kernel_launch(void* const* d_in, const int* in_sizes, int n_in,
                              void* d_out, int out_size, void* d_ws, size_t ws_size,
                              hipStream_t stream) {
    const float* x      = (const float*)d_in[0];
    const float* w_in   = (const float*)d_in[1];
    const float* b_in   = (const float*)d_in[2];
    const float* ln_g   = (const float*)d_in[3];
    const float* ln_b   = (const float*)d_in[4];
    const float* cheb_w = (const float*)d_in[5];
    const float* cheb_b = (const float*)d_in[6];
    const float* bn_g   = (const float*)d_in[7];
    const float* bn_b   = (const float*)d_in[8];
    const float* w1     = (const float*)d_in[9];
    const float* b1     = (const float*)d_in[10];
    const float* w2     = (const float*)d_in[11];
    const float* b2     = (const float*)d_in[12];
    const int*   eidx   = (const int*)d_in[13];
    const int*   batch  = (const int*)d_in[14];
    const int* src = eidx;
    const int* dst = eidx + NEDGES;
    float* out = (float*)d_out;

    char* ws = (char*)d_ws;
    size_t off = 0;
    auto alloc = [&](size_t bytes) -> void* {
        void* p = ws + off;
        off = (off + bytes + 255) & ~(size_t)255;
        return p;
    };
    float* h    = (float*)alloc((size_t)NNODES * 128 * 4);
    float* ob   = (float*)alloc((size_t)NNODES * 128 * 4);
    unsigned short* h16  = (unsigned short*)alloc((size_t)NNODES * 128 * 2);
    unsigned short* t116 = (unsigned short*)alloc((size_t)NNODES * 128 * 2);
    unsigned short* s16  = (unsigned short*)alloc((size_t)NNODES * 128 * 2);
    unsigned short* Wsp  = (unsigned short*)alloc((size_t)10 * 2048 * 16 * 2);
    int* outdeg   = (int*)alloc((size_t)NNODES * 4);
    int* indeg    = (int*)alloc((size_t)NNODES * 4);
    float* dinv   = (float*)alloc((size_t)NNODES * 4);
    int* row_off  = (int*)alloc((size_t)(NNODES + 1) * 4);
    int* cursor   = (int*)alloc((size_t)NNODES * 4);
    int* colv     = (int*)alloc((size_t)NEDGES * 4);
    int* bsum     = (int*)alloc(256 * 4);
    int* gstart   = (int*)alloc((size_t)(NGRAPH + 1) * 4);
    float* colstats = (float*)alloc(256 * 4);
    float* ssbuf    = (float*)alloc(256 * 4);
    double* norm_slots  = (double*)alloc(256 * 8);
    double* cross_slots = (double*)alloc(256 * 8);
    float* colsum = colstats, *colsumsq = colstats + 128;

    hipMemsetAsync(outdeg, 0, (size_t)NNODES * 4, stream);
    hipMemsetAsync(indeg, 0, (size_t)NNODES * 4, stream);
    hipMemsetAsync(norm_slots, 0, 256 * 8, stream);
    hipMemsetAsync(cross_slots, 0, 256 * 8, stream);

    int tE = (NEDGES + 255) / 256;
    int tN = (NNODES + 255) / 256;
    int nb = (NNODES + 255) / 256;     // 196
    deg_kernel<<<tE, 256, 0, stream>>>(src, dst, outdeg, indeg, NEDGES);
    dinv_kernel<<<tN, 256, 0, stream>>>(outdeg, dinv, NNODES);
    scan_part<<<nb, 256, 0, stream>>>(indeg, bsum, NNODES);
    scan_top<<<1, 256, 0, stream>>>(bsum, row_off + NNODES, nb);
    scan_apply<<<nb, 256, 0, stream>>>(indeg, bsum, row_off, cursor, NNODES);
    fill_kernel<<<tE, 256, 0, stream>>>(src, dst, cursor, colv, NEDGES);
    bounds_kernel<<<1, 256, 0, stream>>>(batch, gstart, NNODES);
    wprep_kernel<<<10, 256, 0, stream>>>(w_in, cheb_w, Wsp);

    int gemmBlocks = (NNODES + 63) / 64;
    int waveBlocks = (NNODES * 64 + 255) / 256;

    // embed: h0 = ReLU(LN(x @ w_in + b_in)), fp32 + bf16
    gemm_mfma<1, 0, 1><<<gemmBlocks, 256, 0, stream>>>(x, nullptr, nullptr, Wsp, b_in, h, h16,
                                                       ln_g, ln_b, nullptr, nullptr, NNODES);

    for (int l = 0; l < 3; ++l) {
        hipMemsetAsync(colstats, 0, 256 * 4, stream);
        // t1 = L h  (gather h16) ; fused cross(h), norm(h)
        spmm_kernel<0><<<waveBlocks, 256, 0, stream>>>(h16, h, t116, row_off, colv, dinv,
                                                       outdeg, indeg, NNODES, norm_slots, cross_slots);
        // s = L t1 (gather t116)
        spmm_kernel<1><<<waveBlocks, 256, 0, stream>>>(t116, nullptr, s16, row_off, colv, dinv,
                                                       outdeg, indeg, NNODES, nullptr, nullptr);
        // ob = h(W0-W2) + t1 W1 + s (2W2) + b ; BN col stats
        gemm_mfma<3, 1, 0><<<gemmBlocks, 256, 0, stream>>>(h16, t116, s16,
            Wsp + (size_t)(1 + 3 * l) * 2048 * 16, cheb_b + (size_t)l * 128, ob, nullptr,
            nullptr, nullptr, colsum, colsumsq, NNODES);
        bnscale_kernel<<<1, 128, 0, stream>>>(colsum, colsumsq, bn_g + (size_t)l * 128,
                                              bn_b + (size_t)l * 128, ssbuf, NNODES);
        int total4 = NNODES * 128 / 4;
        bnrelu_kernel<<<(total4 + 255) / 256, 256, 0, stream>>>(ob, ssbuf, h, h16, total4);
    }
    // final hidden's cross + norm
    spmm_kernel<2><<<waveBlocks, 256, 0, stream>>>(h16, h, nullptr, row_off, colv, dinv,
                                                   outdeg, indeg, NNODES, norm_slots, cross_slots);

    poolmlp_kernel<<<NGRAPH, 256, 0, stream>>>(h, gstart, w1, b1, w2, b2,
                                               norm_slots, cross_slots, out);
}